// Round 1
// baseline (363.292 us; speedup 1.0000x reference)
//
#include <hip/hip_runtime.h>
#include <cstdint>
#include <cstddef>

// Problem constants (B,C,H,W)=(4,32,64,64); mamba1: d_model=128, d_in=256,
// dt_rank=8, N=16; mamba2: d_model=2, d_in=4, dt_rank=1.
constexpr int NCH    = 128;   // L / Tchunk
constexpr int TCH    = 32;    // scan chunk length

static __device__ __forceinline__ float sigm_(float x) { return 1.0f / (1.0f + __expf(-x)); }
static __device__ __forceinline__ float silu_(float x) { return x * sigm_(x); }
static __device__ __forceinline__ float softplus_(float x) { return (x > 20.0f) ? x : log1pf(__expf(x)); }

// ---------------------------------------------------------------- prep: A2 = -exp(A_log)*log2(e)
__global__ void k_prep(const float* __restrict__ alog1, const float* __restrict__ alog2,
                       float* __restrict__ A2m1, float* __restrict__ A2m2) {
    int i = blockIdx.x * 256 + threadIdx.x;
    const float LOG2E = 1.4426950408889634f;
    if (i < 4096)       A2m1[i]        = -__expf(alog1[i]) * LOG2E;
    else if (i < 4160)  A2m2[i - 4096] = -__expf(alog2[i - 4096]) * LOG2E;
}

// ---------------------------------------------------------------- gather fo1 -> u (B, 4096, 128)
// u[b,l,0:32]=h_fwd, 32:64=h_bwd, 64:96=w_fwd, 96:128=w_bwd
__global__ __launch_bounds__(256) void k_gather(const float* __restrict__ fo1, float* __restrict__ u) {
    __shared__ float lds[32][65];
    int blk = blockIdx.x;          // 4*64 blocks: (b, h)
    int b = blk >> 6, h = blk & 63;
    int tid = threadIdx.x;
    {
        int w = tid & 63, cs = tid >> 6;           // cs 0..3 -> 8 c each
        const float* src = fo1 + (size_t)(b * 32) * 4096 + h * 64 + w;
        #pragma unroll
        for (int j = 0; j < 8; ++j) {
            int c = cs * 8 + j;
            lds[c][w] = src[(size_t)c * 4096];
        }
    }
    __syncthreads();
    {
        int c = tid & 31, wsub = tid >> 5;         // wsub 0..7 -> 8 w each
        #pragma unroll
        for (int j = 0; j < 8; ++j) {
            int w = wsub * 8 + j;
            float v = lds[c][w];
            int l  = h * 64 + w;     // row-major position
            int l2 = w * 64 + h;     // col-major position
            u[(size_t)(b * 4096 + l)        * 128 +       c] = v;
            u[(size_t)(b * 4096 + 4095 - l) * 128 + 32  + c] = v;
            u[(size_t)(b * 4096 + l2)       * 128 + 64  + c] = v;
            u[(size_t)(b * 4096 + 4095 - l2)* 128 + 96  + c] = v;
        }
    }
}

// ---------------------------------------------------------------- generic fp32 GEMM  C = A @ W^T
// A: (M,K) row-major; W: (N,K) row-major; C: (M,N). M%64==0, K%32==0. N masked.
__global__ __launch_bounds__(256) void k_gemm_nt(const float* __restrict__ A, const float* __restrict__ W,
                                                 float* __restrict__ Cmat, int M, int N, int K) {
    __shared__ float As[64][36];
    __shared__ float Ws[64][36];
    int n0 = blockIdx.x * 64, m0 = blockIdx.y * 64;
    int tid = threadIdx.x;
    int tx = tid & 15, ty = tid >> 4;
    float acc[4][4];
    #pragma unroll
    for (int i = 0; i < 4; ++i)
        #pragma unroll
        for (int j = 0; j < 4; ++j) acc[i][j] = 0.f;
    int kk = tid & 31, rr = tid >> 5;
    for (int k0 = 0; k0 < K; k0 += 32) {
        #pragma unroll
        for (int j = 0; j < 8; ++j) {
            int r = rr + j * 8;
            As[r][kk] = A[(size_t)(m0 + r) * K + k0 + kk];
            float v = 0.f;
            if (n0 + r < N) v = W[(size_t)(n0 + r) * K + k0 + kk];
            Ws[r][kk] = v;
        }
        __syncthreads();
        #pragma unroll
        for (int kq = 0; kq < 32; kq += 4) {
            float4 a4[4], w4[4];
            #pragma unroll
            for (int i = 0; i < 4; ++i) a4[i] = *(const float4*)&As[ty + 16 * i][kq];
            #pragma unroll
            for (int j = 0; j < 4; ++j) w4[j] = *(const float4*)&Ws[tx + 16 * j][kq];
            #pragma unroll
            for (int i = 0; i < 4; ++i)
                #pragma unroll
                for (int j = 0; j < 4; ++j)
                    acc[i][j] += a4[i].x * w4[j].x + a4[i].y * w4[j].y +
                                 a4[i].z * w4[j].z + a4[i].w * w4[j].w;
        }
        __syncthreads();
    }
    #pragma unroll
    for (int i = 0; i < 4; ++i) {
        size_t mrow = (size_t)(m0 + ty + 16 * i) * N;
        #pragma unroll
        for (int j = 0; j < 4; ++j) {
            int n = n0 + tx + 16 * j;
            if (n < N) Cmat[mrow + n] = acc[i][j];
        }
    }
}

// ---------------------------------------------------------------- depthwise causal conv(4) + SiLU
// xz: (B*L, 512) rows; x part = cols 0..255. Out x: (B*L, 256).
__global__ __launch_bounds__(256) void k_conv(const float* __restrict__ xz, const float* __restrict__ cw,
                                              const float* __restrict__ cb, float* __restrict__ x) {
    int blk = blockIdx.x;          // b*4096 + l
    int d = threadIdx.x;
    int l = blk & 4095;
    const float* base = xz + (size_t)blk * 512 + d;
    float acc = cb[d] + cw[d * 4 + 3] * base[0];
    if (l >= 1) acc += cw[d * 4 + 2] * base[-512];
    if (l >= 2) acc += cw[d * 4 + 1] * base[-1024];
    if (l >= 3) acc += cw[d * 4 + 0] * base[-1536];
    x[(size_t)blk * 256 + d] = silu_(acc);
}

// ---------------------------------------------------------------- dt = softplus(dbl[:, :8] @ dt_w^T + dt_b)
__global__ __launch_bounds__(256) void k_dtproj(const float* __restrict__ dbl, const float* __restrict__ dtw,
                                                const float* __restrict__ dtb, float* __restrict__ dt) {
    int blk = blockIdx.x;          // b*4096 + l
    int d = threadIdx.x;
    const float* r = dbl + (size_t)blk * 40;
    float4 q0 = *(const float4*)(r);
    float4 q1 = *(const float4*)(r + 4);
    float4 w0 = *(const float4*)(dtw + d * 8);
    float4 w1 = *(const float4*)(dtw + d * 8 + 4);
    float v = q0.x * w0.x + q0.y * w0.y + q0.z * w0.z + q0.w * w0.w +
              q1.x * w1.x + q1.y * w1.y + q1.z * w1.z + q1.w * w1.w + dtb[d];
    dt[(size_t)blk * 256 + d] = softplus_(v);
}

// ---------------------------------------------------------------- scan phase 1: per-chunk (P, S)
__global__ __launch_bounds__(256) void k_scan1(const float* __restrict__ dt, const float* __restrict__ x,
                                               const float* __restrict__ dbl, const float* __restrict__ A2,
                                               float* __restrict__ P, float* __restrict__ S) {
    int blk = blockIdx.x;          // b*NCH + ch
    int b = blk / NCH, ch = blk % NCH;
    int d = threadIdx.x;
    float a2[16], h[16], p[16];
    #pragma unroll
    for (int n = 0; n < 16; ++n) { a2[n] = A2[d * 16 + n]; h[n] = 0.f; p[n] = 1.f; }
    int t0 = ch * TCH;
    for (int t = t0; t < t0 + TCH; ++t) {
        size_t row = (size_t)(b * 4096 + t);
        float dtv = dt[row * 256 + d];
        float xv  = x[row * 256 + d];
        const float* br = dbl + row * 40 + 8;
        float4 b0 = *(const float4*)(br), b1 = *(const float4*)(br + 4),
               b2 = *(const float4*)(br + 8), b3 = *(const float4*)(br + 12);
        float bm[16] = {b0.x, b0.y, b0.z, b0.w, b1.x, b1.y, b1.z, b1.w,
                        b2.x, b2.y, b2.z, b2.w, b3.x, b3.y, b3.z, b3.w};
        float dx = dtv * xv;
        #pragma unroll
        for (int n = 0; n < 16; ++n) {
            float a = exp2f(dtv * a2[n]);
            h[n] = a * h[n] + dx * bm[n];
            p[n] *= a;
        }
    }
    size_t o = ((size_t)blk * 256 + d) * 16;
    #pragma unroll
    for (int n = 0; n < 16; n += 4) {
        *(float4*)&P[o + n] = make_float4(p[n], p[n + 1], p[n + 2], p[n + 3]);
        *(float4*)&S[o + n] = make_float4(h[n], h[n + 1], h[n + 2], h[n + 3]);
    }
}

// ---------------------------------------------------------------- scan phase 2: carry scan over chunks
__global__ __launch_bounds__(256) void k_scan2(const float* __restrict__ P, const float* __restrict__ S,
                                               float* __restrict__ carry) {
    int tid = blockIdx.x * 256 + threadIdx.x;   // 16384 = B*256*16
    int b = tid >> 12;
    int dn = tid & 4095;
    float c = 0.f;
    for (int ch = 0; ch < NCH; ++ch) {
        size_t o = (size_t)(b * NCH + ch) * 4096 + dn;
        carry[o] = c;
        c = P[o] * c + S[o];
    }
}

// ---------------------------------------------------------------- scan phase 3: replay + fused epilogue
__global__ __launch_bounds__(256) void k_scan3(const float* __restrict__ dt, const float* __restrict__ x,
                                               const float* __restrict__ xz, const float* __restrict__ dbl,
                                               const float* __restrict__ A2, const float* __restrict__ carry,
                                               const float* __restrict__ Dp, float* __restrict__ y) {
    int blk = blockIdx.x;
    int b = blk / NCH, ch = blk % NCH;
    int d = threadIdx.x;
    float a2[16], h[16];
    size_t co = ((size_t)blk * 256 + d) * 16;
    #pragma unroll
    for (int n = 0; n < 16; n += 4) {
        float4 v = *(const float4*)&carry[co + n];
        h[n] = v.x; h[n + 1] = v.y; h[n + 2] = v.z; h[n + 3] = v.w;
    }
    #pragma unroll
    for (int n = 0; n < 16; ++n) a2[n] = A2[d * 16 + n];
    float Dd = Dp[d];
    int t0 = ch * TCH;
    for (int t = t0; t < t0 + TCH; ++t) {
        size_t row = (size_t)(b * 4096 + t);
        float dtv = dt[row * 256 + d];
        float xv  = x[row * 256 + d];
        float zv  = xz[row * 512 + 256 + d];
        const float* br = dbl + row * 40 + 8;
        float4 b0 = *(const float4*)(br), b1 = *(const float4*)(br + 4),
               b2 = *(const float4*)(br + 8), b3 = *(const float4*)(br + 12);
        float4 c0 = *(const float4*)(br + 16), c1 = *(const float4*)(br + 20),
               c2 = *(const float4*)(br + 24), c3 = *(const float4*)(br + 28);
        float bm[16] = {b0.x, b0.y, b0.z, b0.w, b1.x, b1.y, b1.z, b1.w,
                        b2.x, b2.y, b2.z, b2.w, b3.x, b3.y, b3.z, b3.w};
        float cm[16] = {c0.x, c0.y, c0.z, c0.w, c1.x, c1.y, c1.z, c1.w,
                        c2.x, c2.y, c2.z, c2.w, c3.x, c3.y, c3.z, c3.w};
        float dx = dtv * xv;
        float yv = 0.f;
        #pragma unroll
        for (int n = 0; n < 16; ++n) {
            float a = exp2f(dtv * a2[n]);
            h[n] = a * h[n] + dx * bm[n];
            yv += h[n] * cm[n];
        }
        yv = (yv + xv * Dd) * silu_(zv);
        y[row * 256 + d] = yv;
    }
}

// ---------------------------------------------------------------- group-sum(4) + residual = (.)*fo2
__global__ __launch_bounds__(256) void k_gsum(const float* __restrict__ opre, const float* __restrict__ fo2,
                                              float* __restrict__ res) {
    __shared__ float s[64][33];
    int blk = blockIdx.x;          // 4*64: (b, l-chunk)
    int b = blk >> 6, lc = blk & 63;
    int tid = threadIdx.x;
    {
        int c = tid & 31, ls = tid >> 5;
        #pragma unroll
        for (int j = 0; j < 8; ++j) {
            int ll = ls * 8 + j;
            const float* r = opre + (size_t)(b * 4096 + lc * 64 + ll) * 128 + c;
            s[ll][c] = r[0] + r[32] + r[64] + r[96];
        }
    }
    __syncthreads();
    {
        int w = tid & 63, cs = tid >> 6;
        #pragma unroll
        for (int j = 0; j < 8; ++j) {
            int c = cs * 8 + j;
            size_t o = (size_t)(b * 32 + c) * 4096 + lc * 64 + w;
            res[o] = s[w][c] * fo2[o];
        }
    }
}

// ---------------------------------------------------------------- per-(b,c) mean over HW
__global__ __launch_bounds__(256) void k_rowmean(const float* __restrict__ res, float* __restrict__ foc0) {
    int bc = blockIdx.x;           // 128
    int tid = threadIdx.x;
    const float* r = res + (size_t)bc * 4096;
    float sum = 0.f;
    #pragma unroll
    for (int j = 0; j < 4; ++j) {
        float4 v = *(const float4*)&r[(j * 256 + tid) * 4];
        sum += v.x + v.y + v.z + v.w;
    }
    __shared__ float wsum[4];
    int lane = tid & 63, wv = tid >> 6;
    #pragma unroll
    for (int m = 32; m > 0; m >>= 1) sum += __shfl_xor(sum, m, 64);
    if (lane == 0) wsum[wv] = sum;
    __syncthreads();
    if (tid == 0) foc0[bc] = (wsum[0] + wsum[1] + wsum[2] + wsum[3]) * (1.0f / 4096.0f);
}

// ---------------------------------------------------------------- tiny mamba2, single block
__global__ __launch_bounds__(256) void k_mamba2(const float* __restrict__ foc0,
                                                const float* __restrict__ in_w, const float* __restrict__ cw,
                                                const float* __restrict__ cb, const float* __restrict__ xw,
                                                const float* __restrict__ dtw, const float* __restrict__ dtb,
                                                const float* __restrict__ A2, const float* __restrict__ Dp,
                                                const float* __restrict__ ow, float* __restrict__ focf) {
    __shared__ float xz2[4][32][8];
    __shared__ float x2c[4][32][4];
    __shared__ float dbl2[4][32][33];
    __shared__ float dt2[4][32][4];
    __shared__ float y2[4][32][4];
    int tid = threadIdx.x;
    // in-proj on u2 = [foc0[b,l], foc0[b,31-l]]
    for (int i = tid; i < 4 * 32 * 8; i += 256) {
        int b = i >> 8, l = (i >> 3) & 31, j = i & 7;
        float u0 = foc0[b * 32 + l], u1 = foc0[b * 32 + 31 - l];
        xz2[b][l][j] = u0 * in_w[j * 2] + u1 * in_w[j * 2 + 1];
    }
    __syncthreads();
    // conv + silu
    for (int i = tid; i < 4 * 32 * 4; i += 256) {
        int b = i >> 7, l = (i >> 2) & 31, d = i & 3;
        float acc = cb[d] + cw[d * 4 + 3] * xz2[b][l][d];
        if (l >= 1) acc += cw[d * 4 + 2] * xz2[b][l - 1][d];
        if (l >= 2) acc += cw[d * 4 + 1] * xz2[b][l - 2][d];
        if (l >= 3) acc += cw[d * 4 + 0] * xz2[b][l - 3][d];
        x2c[b][l][d] = silu_(acc);
    }
    __syncthreads();
    // x-proj (33 outs)
    for (int i = tid; i < 4 * 32 * 33; i += 256) {
        int b = i / (32 * 33); int rem = i % (32 * 33); int l = rem / 33; int j = rem % 33;
        float s = 0.f;
        #pragma unroll
        for (int d = 0; d < 4; ++d) s += x2c[b][l][d] * xw[j * 4 + d];
        dbl2[b][l][j] = s;
    }
    __syncthreads();
    // dt
    for (int i = tid; i < 4 * 32 * 4; i += 256) {
        int b = i >> 7, l = (i >> 2) & 31, d = i & 3;
        dt2[b][l][d] = softplus_(dbl2[b][l][0] * dtw[d] + dtb[d]);
    }
    __syncthreads();
    // scan: thread = (b,d,n)
    {
        int b = tid >> 6, d = (tid >> 4) & 3, n = tid & 15;
        float a2v = A2[d * 16 + n];
        float h = 0.f;
        for (int t = 0; t < 32; ++t) {
            float dtv = dt2[b][t][d];
            float a = exp2f(dtv * a2v);
            h = a * h + dtv * x2c[b][t][d] * dbl2[b][t][1 + n];
            float contrib = h * dbl2[b][t][17 + n];
            contrib += __shfl_xor(contrib, 1, 64);
            contrib += __shfl_xor(contrib, 2, 64);
            contrib += __shfl_xor(contrib, 4, 64);
            contrib += __shfl_xor(contrib, 8, 64);
            if (n == 0) y2[b][t][d] = contrib;
        }
    }
    __syncthreads();
    // gate + out-proj + sum(2)
    if (tid < 128) {
        int b = tid >> 5, l = tid & 31;
        float s = 0.f;
        #pragma unroll
        for (int d = 0; d < 4; ++d) {
            float yg = (y2[b][l][d] + x2c[b][l][d] * Dp[d]) * silu_(xz2[b][l][4 + d]);
            s += yg * (ow[d] + ow[4 + d]);
        }
        focf[b * 32 + l] = s;
    }
}

// ---------------------------------------------------------------- final: out = res*(1+foc)
__global__ __launch_bounds__(256) void k_final(const float* __restrict__ res, const float* __restrict__ focf,
                                               float* __restrict__ out) {
    int i = blockIdx.x * 256 + threadIdx.x;
    int bc = i >> 12;
    out[i] = res[i] * (1.0f + focf[bc]);
}

extern "C" void kernel_launch(void* const* d_in, const int* in_sizes, int n_in,
                              void* d_out, int out_size, void* d_ws, size_t ws_size,
                              hipStream_t stream) {
    const float* fo1      = (const float*)d_in[0];
    const float* fo2      = (const float*)d_in[1];
    const float* m1_in_w  = (const float*)d_in[2];
    const float* m1_cw    = (const float*)d_in[3];
    const float* m1_cb    = (const float*)d_in[4];
    const float* m1_xw    = (const float*)d_in[5];
    const float* m1_dtw   = (const float*)d_in[6];
    const float* m1_dtb   = (const float*)d_in[7];
    const float* m1_alog  = (const float*)d_in[8];
    const float* m1_D     = (const float*)d_in[9];
    const float* m1_ow    = (const float*)d_in[10];
    const float* m2_in_w  = (const float*)d_in[11];
    const float* m2_cw    = (const float*)d_in[12];
    const float* m2_cb    = (const float*)d_in[13];
    const float* m2_xw    = (const float*)d_in[14];
    const float* m2_dtw   = (const float*)d_in[15];
    const float* m2_dtb   = (const float*)d_in[16];
    const float* m2_alog  = (const float*)d_in[17];
    const float* m2_D     = (const float*)d_in[18];
    const float* m2_ow    = (const float*)d_in[19];

    float* ws = (float*)d_ws;
    // workspace layout (floats); total ~26.35M floats = ~105 MB
    float* u     = ws;                 // 2,097,152   (reused later as out_pre)
    float* xz    = ws + 2097152;       // 8,388,608
    float* xbuf  = ws + 10485760;      // 4,194,304
    float* dbl   = ws + 14680064;      // 655,360
    float* dtbuf = ws + 15335424;      // 4,194,304
    float* Pb    = ws + 19529728;      // 2,097,152  \ aliased by ybuf after scan2
    float* Sb    = ws + 21626880;      // 2,097,152  /
    float* ybuf  = ws + 19529728;      // 4,194,304  (over P+S; P/S dead after scan2)
    float* carry = ws + 23724032;      // 2,097,152
    float* res   = ws + 25821184;      // 524,288
    float* foc0  = ws + 26345472;      // 128
    float* focf  = ws + 26345600;      // 128
    float* A2m1  = ws + 26345728;      // 4,096
    float* A2m2  = ws + 26349824;      // 64
    float* opre  = u;                  // u dead after gemm1

    k_prep<<<17, 256, 0, stream>>>(m1_alog, m2_alog, A2m1, A2m2);
    k_gather<<<256, 256, 0, stream>>>(fo1, u);
    {   dim3 g(8, 256);  k_gemm_nt<<<g, 256, 0, stream>>>(u, m1_in_w, xz, 16384, 512, 128); }
    k_conv<<<16384, 256, 0, stream>>>(xz, m1_cw, m1_cb, xbuf);
    {   dim3 g(1, 256);  k_gemm_nt<<<g, 256, 0, stream>>>(xbuf, m1_xw, dbl, 16384, 40, 256); }
    k_dtproj<<<16384, 256, 0, stream>>>(dbl, m1_dtw, m1_dtb, dtbuf);
    k_scan1<<<4 * NCH, 256, 0, stream>>>(dtbuf, xbuf, dbl, A2m1, Pb, Sb);
    k_scan2<<<64, 256, 0, stream>>>(Pb, Sb, carry);
    k_scan3<<<4 * NCH, 256, 0, stream>>>(dtbuf, xbuf, xz, dbl, A2m1, carry, m1_D, ybuf);
    {   dim3 g(2, 256);  k_gemm_nt<<<g, 256, 0, stream>>>(ybuf, m1_ow, opre, 16384, 128, 256); }
    k_gsum<<<256, 256, 0, stream>>>(opre, fo2, res);
    k_rowmean<<<128, 256, 0, stream>>>(res, foc0);
    k_mamba2<<<1, 256, 0, stream>>>(foc0, m2_in_w, m2_cw, m2_cb, m2_xw, m2_dtw, m2_dtb,
                                    A2m2, m2_D, m2_ow, focf);
    k_final<<<2048, 256, 0, stream>>>(res, focf, (float*)d_out);
}

// Round 2
// 268.447 us; speedup vs baseline: 1.3533x; 1.3533x over previous
//
#include <hip/hip_runtime.h>
#include <cstdint>
#include <cstddef>

// (B,C,H,W)=(4,32,64,64); mamba1: d_model=128, d_in=256, dt_rank=8, N=16;
// mamba2: d_model=2, d_in=4, dt_rank=1.
constexpr int NCH = 128;   // L / Tchunk
constexpr int TCH = 32;    // scan chunk length

typedef __attribute__((ext_vector_type(8))) short bf16x8;
typedef __attribute__((ext_vector_type(4))) float f32x4;

static __device__ __forceinline__ float sigm_(float x) { return 1.0f / (1.0f + __expf(-x)); }
static __device__ __forceinline__ float silu_(float x) { return x * sigm_(x); }
static __device__ __forceinline__ float softplus_(float x) { return (x > 20.0f) ? x : log1pf(__expf(x)); }
static __device__ __forceinline__ unsigned short f2bf(float f) {
    union { float f; unsigned int u; } v; v.f = f;
    unsigned int r = v.u + 0x7FFFu + ((v.u >> 16) & 1u);
    return (unsigned short)(r >> 16);
}

// ---------------------------------------------------------------- prep: A2 = -exp(A_log)*log2(e); weight bf16 casts
__global__ void k_prep(const float* __restrict__ alog1, const float* __restrict__ alog2,
                       const float* __restrict__ w_in, const float* __restrict__ w_x,
                       const float* __restrict__ w_o,
                       float* __restrict__ A2m1, float* __restrict__ A2m2,
                       unsigned short* __restrict__ win_bf, unsigned short* __restrict__ wx_bf,
                       unsigned short* __restrict__ wo_bf) {
    int i = blockIdx.x * 256 + threadIdx.x;
    const float LOG2E = 1.4426950408889634f;
    if (i < 4096)        A2m1[i] = -__expf(alog1[i]) * LOG2E;
    else if (i < 4160)   A2m2[i - 4096] = -__expf(alog2[i - 4096]) * LOG2E;
    else if (i < 69696)  win_bf[i - 4160]  = f2bf(w_in[i - 4160]);    // 512*128
    else if (i < 79936)  wx_bf[i - 69696]  = f2bf(w_x[i - 69696]);    // 40*256
    else if (i < 112704) wo_bf[i - 79936]  = f2bf(w_o[i - 79936]);    // 128*256
}

// ---------------------------------------------------------------- gather fo1 -> u bf16 (B, 4096, 128)
__global__ __launch_bounds__(256) void k_gather(const float* __restrict__ fo1, unsigned short* __restrict__ u) {
    __shared__ float lds[32][65];
    int blk = blockIdx.x;          // 4*64 blocks: (b, h)
    int b = blk >> 6, h = blk & 63;
    int tid = threadIdx.x;
    {
        int w = tid & 63, cs = tid >> 6;
        const float* src = fo1 + (size_t)(b * 32) * 4096 + h * 64 + w;
        #pragma unroll
        for (int j = 0; j < 8; ++j) {
            int c = cs * 8 + j;
            lds[c][w] = src[(size_t)c * 4096];
        }
    }
    __syncthreads();
    {
        int c = tid & 31, wsub = tid >> 5;
        #pragma unroll
        for (int j = 0; j < 8; ++j) {
            int w = wsub * 8 + j;
            unsigned short v = f2bf(lds[c][w]);
            int l  = h * 64 + w;
            int l2 = w * 64 + h;
            u[(size_t)(b * 4096 + l)        * 128 +       c] = v;
            u[(size_t)(b * 4096 + 4095 - l) * 128 + 32  + c] = v;
            u[(size_t)(b * 4096 + l2)       * 128 + 64  + c] = v;
            u[(size_t)(b * 4096 + 4095 - l2)* 128 + 96  + c] = v;
        }
    }
}

// ---------------------------------------------------------------- MFMA bf16 GEMM  C = A @ W^T (fp32 out)
// A: (M,K) bf16 row-major; W: (N,K) bf16 row-major; C: (M,N) fp32. M%128==0, K%32==0. N masked.
__global__ __launch_bounds__(256) void k_gemm_mfma(const unsigned short* __restrict__ A,
                                                   const unsigned short* __restrict__ W,
                                                   float* __restrict__ Cmat, int M, int N, int K) {
    __shared__ unsigned short As[128][40];   // 80B row stride: 16B-aligned, 2-way bank alias (free)
    __shared__ unsigned short Ws[128][40];
    int n0 = blockIdx.x * 128, m0 = blockIdx.y * 128;
    int tid = threadIdx.x;
    int lane = tid & 63, wv = tid >> 6;
    int mh = wv >> 1, nh = wv & 1;
    int lm = lane & 15, quad = lane >> 4;

    f32x4 acc[4][4];
    #pragma unroll
    for (int i = 0; i < 4; ++i)
        #pragma unroll
        for (int j = 0; j < 4; ++j) acc[i][j] = (f32x4)(0.0f);

    for (int k0 = 0; k0 < K; k0 += 32) {
        #pragma unroll
        for (int j = 0; j < 2; ++j) {
            int c = tid + 256 * j;         // 0..511
            int row = c >> 2;
            int kc = (c & 3) * 8;
            uint4 av = *(const uint4*)&A[(size_t)(m0 + row) * K + k0 + kc];
            *(uint4*)&As[row][kc] = av;
            uint4 wvv = make_uint4(0u, 0u, 0u, 0u);
            if (n0 + row < N) wvv = *(const uint4*)&W[(size_t)(n0 + row) * K + k0 + kc];
            *(uint4*)&Ws[row][kc] = wvv;
        }
        __syncthreads();
        bf16x8 a_frag[4], b_frag[4];
        #pragma unroll
        for (int i = 0; i < 4; ++i)
            a_frag[i] = *(const bf16x8*)&As[mh * 64 + 16 * i + lm][quad * 8];
        #pragma unroll
        for (int j = 0; j < 4; ++j)
            b_frag[j] = *(const bf16x8*)&Ws[nh * 64 + 16 * j + lm][quad * 8];
        #pragma unroll
        for (int i = 0; i < 4; ++i)
            #pragma unroll
            for (int j = 0; j < 4; ++j)
                acc[i][j] = __builtin_amdgcn_mfma_f32_16x16x32_bf16(a_frag[i], b_frag[j], acc[i][j], 0, 0, 0);
        __syncthreads();
    }
    // C/D layout: col = lane&15, row = quad*4 + reg  (m89/m91-verified)
    #pragma unroll
    for (int i = 0; i < 4; ++i) {
        #pragma unroll
        for (int r = 0; r < 4; ++r) {
            size_t mrow = (size_t)(m0 + mh * 64 + 16 * i + quad * 4 + r) * N;
            #pragma unroll
            for (int j = 0; j < 4; ++j) {
                int col = n0 + nh * 64 + 16 * j + lm;
                if (col < N) Cmat[mrow + col] = acc[i][j][r];
            }
        }
    }
}

// ---------------------------------------------------------------- depthwise causal conv(4) + SiLU (fp32 + bf16 out)
__global__ __launch_bounds__(256) void k_conv(const float* __restrict__ xz, const float* __restrict__ cw,
                                              const float* __restrict__ cb, float* __restrict__ x,
                                              unsigned short* __restrict__ xbf) {
    int blk = blockIdx.x;          // b*4096 + l
    int d = threadIdx.x;
    int l = blk & 4095;
    const float* base = xz + (size_t)blk * 512 + d;
    float acc = cb[d] + cw[d * 4 + 3] * base[0];
    if (l >= 1) acc += cw[d * 4 + 2] * base[-512];
    if (l >= 2) acc += cw[d * 4 + 1] * base[-1024];
    if (l >= 3) acc += cw[d * 4 + 0] * base[-1536];
    float v = silu_(acc);
    x[(size_t)blk * 256 + d] = v;
    xbf[(size_t)blk * 256 + d] = f2bf(v);
}

// ---------------------------------------------------------------- dt = softplus(dbl[:, :8] @ dt_w^T + dt_b)
__global__ __launch_bounds__(256) void k_dtproj(const float* __restrict__ dbl, const float* __restrict__ dtw,
                                                const float* __restrict__ dtb, float* __restrict__ dt) {
    int blk = blockIdx.x;
    int d = threadIdx.x;
    const float* r = dbl + (size_t)blk * 40;
    float4 q0 = *(const float4*)(r);
    float4 q1 = *(const float4*)(r + 4);
    float4 w0 = *(const float4*)(dtw + d * 8);
    float4 w1 = *(const float4*)(dtw + d * 8 + 4);
    float v = q0.x * w0.x + q0.y * w0.y + q0.z * w0.z + q0.w * w0.w +
              q1.x * w1.x + q1.y * w1.y + q1.z * w1.z + q1.w * w1.w + dtb[d];
    dt[(size_t)blk * 256 + d] = softplus_(v);
}

// ---------------------------------------------------------------- scan phase 1: per-chunk (P, S)
__global__ __launch_bounds__(256) void k_scan1(const float* __restrict__ dt, const float* __restrict__ x,
                                               const float* __restrict__ dbl, const float* __restrict__ A2,
                                               float* __restrict__ P, float* __restrict__ S) {
    int blk = blockIdx.x;          // b*NCH + ch
    int b = blk / NCH, ch = blk % NCH;
    int d = threadIdx.x;
    float a2[16], h[16], p[16];
    #pragma unroll
    for (int n = 0; n < 16; ++n) { a2[n] = A2[d * 16 + n]; h[n] = 0.f; p[n] = 1.f; }
    int t0 = ch * TCH;
    for (int t = t0; t < t0 + TCH; ++t) {
        size_t row = (size_t)(b * 4096 + t);
        float dtv = dt[row * 256 + d];
        float xv  = x[row * 256 + d];
        const float* br = dbl + row * 40 + 8;
        float4 b0 = *(const float4*)(br), b1 = *(const float4*)(br + 4),
               b2 = *(const float4*)(br + 8), b3 = *(const float4*)(br + 12);
        float bm[16] = {b0.x, b0.y, b0.z, b0.w, b1.x, b1.y, b1.z, b1.w,
                        b2.x, b2.y, b2.z, b2.w, b3.x, b3.y, b3.z, b3.w};
        float dx = dtv * xv;
        #pragma unroll
        for (int n = 0; n < 16; ++n) {
            float a = exp2f(dtv * a2[n]);
            h[n] = a * h[n] + dx * bm[n];
            p[n] *= a;
        }
    }
    size_t o = ((size_t)blk * 256 + d) * 16;
    #pragma unroll
    for (int n = 0; n < 16; n += 4) {
        *(float4*)&P[o + n] = make_float4(p[n], p[n + 1], p[n + 2], p[n + 3]);
        *(float4*)&S[o + n] = make_float4(h[n], h[n + 1], h[n + 2], h[n + 3]);
    }
}

// ---------------------------------------------------------------- scan phase 2: carry scan over chunks
// NOTE: carry may alias S (read-before-write per index); no __restrict__ here.
__global__ __launch_bounds__(256) void k_scan2(const float* __restrict__ P, const float* S,
                                               float* carry) {
    int tid = blockIdx.x * 256 + threadIdx.x;   // 16384 = B*256*16
    int b = tid >> 12;
    int dn = tid & 4095;
    float c = 0.f;
    for (int ch = 0; ch < NCH; ++ch) {
        size_t o = (size_t)(b * NCH + ch) * 4096 + dn;
        float p = P[o];
        float s = S[o];
        carry[o] = c;
        c = p * c + s;
    }
}

// ---------------------------------------------------------------- scan phase 3: replay + fused epilogue (bf16 y out)
__global__ __launch_bounds__(256) void k_scan3(const float* __restrict__ dt, const float* __restrict__ x,
                                               const float* __restrict__ xz, const float* __restrict__ dbl,
                                               const float* __restrict__ A2, const float* __restrict__ carry,
                                               const float* __restrict__ Dp, unsigned short* __restrict__ y) {
    int blk = blockIdx.x;
    int b = blk / NCH, ch = blk % NCH;
    int d = threadIdx.x;
    float a2[16], h[16];
    size_t co = ((size_t)blk * 256 + d) * 16;
    #pragma unroll
    for (int n = 0; n < 16; n += 4) {
        float4 v = *(const float4*)&carry[co + n];
        h[n] = v.x; h[n + 1] = v.y; h[n + 2] = v.z; h[n + 3] = v.w;
    }
    #pragma unroll
    for (int n = 0; n < 16; ++n) a2[n] = A2[d * 16 + n];
    float Dd = Dp[d];
    int t0 = ch * TCH;
    for (int t = t0; t < t0 + TCH; ++t) {
        size_t row = (size_t)(b * 4096 + t);
        float dtv = dt[row * 256 + d];
        float xv  = x[row * 256 + d];
        float zv  = xz[row * 512 + 256 + d];
        const float* br = dbl + row * 40 + 8;
        float4 b0 = *(const float4*)(br), b1 = *(const float4*)(br + 4),
               b2 = *(const float4*)(br + 8), b3 = *(const float4*)(br + 12);
        float4 c0 = *(const float4*)(br + 16), c1 = *(const float4*)(br + 20),
               c2 = *(const float4*)(br + 24), c3 = *(const float4*)(br + 28);
        float bm[16] = {b0.x, b0.y, b0.z, b0.w, b1.x, b1.y, b1.z, b1.w,
                        b2.x, b2.y, b2.z, b2.w, b3.x, b3.y, b3.z, b3.w};
        float cm[16] = {c0.x, c0.y, c0.z, c0.w, c1.x, c1.y, c1.z, c1.w,
                        c2.x, c2.y, c2.z, c2.w, c3.x, c3.y, c3.z, c3.w};
        float dx = dtv * xv;
        float yv = 0.f;
        #pragma unroll
        for (int n = 0; n < 16; ++n) {
            float a = exp2f(dtv * a2[n]);
            h[n] = a * h[n] + dx * bm[n];
            yv += h[n] * cm[n];
        }
        yv = (yv + xv * Dd) * silu_(zv);
        y[row * 256 + d] = f2bf(yv);
    }
}

// ---------------------------------------------------------------- group-sum(4) + residual = (.)*fo2
__global__ __launch_bounds__(256) void k_gsum(const float* __restrict__ opre, const float* __restrict__ fo2,
                                              float* __restrict__ res) {
    __shared__ float s[64][33];
    int blk = blockIdx.x;          // 4*64: (b, l-chunk)
    int b = blk >> 6, lc = blk & 63;
    int tid = threadIdx.x;
    {
        int c = tid & 31, ls = tid >> 5;
        #pragma unroll
        for (int j = 0; j < 8; ++j) {
            int ll = ls * 8 + j;
            const float* r = opre + (size_t)(b * 4096 + lc * 64 + ll) * 128 + c;
            s[ll][c] = r[0] + r[32] + r[64] + r[96];
        }
    }
    __syncthreads();
    {
        int w = tid & 63, cs = tid >> 6;
        #pragma unroll
        for (int j = 0; j < 8; ++j) {
            int c = cs * 8 + j;
            size_t o = (size_t)(b * 32 + c) * 4096 + lc * 64 + w;
            res[o] = s[w][c] * fo2[o];
        }
    }
}

// ---------------------------------------------------------------- per-(b,c) mean over HW
__global__ __launch_bounds__(256) void k_rowmean(const float* __restrict__ res, float* __restrict__ foc0) {
    int bc = blockIdx.x;           // 128
    int tid = threadIdx.x;
    const float* r = res + (size_t)bc * 4096;
    float sum = 0.f;
    #pragma unroll
    for (int j = 0; j < 4; ++j) {
        float4 v = *(const float4*)&r[(j * 256 + tid) * 4];
        sum += v.x + v.y + v.z + v.w;
    }
    __shared__ float wsum[4];
    int lane = tid & 63, wv = tid >> 6;
    #pragma unroll
    for (int m = 32; m > 0; m >>= 1) sum += __shfl_xor(sum, m, 64);
    if (lane == 0) wsum[wv] = sum;
    __syncthreads();
    if (tid == 0) foc0[bc] = (wsum[0] + wsum[1] + wsum[2] + wsum[3]) * (1.0f / 4096.0f);
}

// ---------------------------------------------------------------- tiny mamba2, single block
__global__ __launch_bounds__(256) void k_mamba2(const float* __restrict__ foc0,
                                                const float* __restrict__ in_w, const float* __restrict__ cw,
                                                const float* __restrict__ cb, const float* __restrict__ xw,
                                                const float* __restrict__ dtw, const float* __restrict__ dtb,
                                                const float* __restrict__ A2, const float* __restrict__ Dp,
                                                const float* __restrict__ ow, float* __restrict__ focf) {
    __shared__ float xz2[4][32][8];
    __shared__ float x2c[4][32][4];
    __shared__ float dbl2[4][32][33];
    __shared__ float dt2[4][32][4];
    __shared__ float y2[4][32][4];
    int tid = threadIdx.x;
    for (int i = tid; i < 4 * 32 * 8; i += 256) {
        int b = i >> 8, l = (i >> 3) & 31, j = i & 7;
        float u0 = foc0[b * 32 + l], u1 = foc0[b * 32 + 31 - l];
        xz2[b][l][j] = u0 * in_w[j * 2] + u1 * in_w[j * 2 + 1];
    }
    __syncthreads();
    for (int i = tid; i < 4 * 32 * 4; i += 256) {
        int b = i >> 7, l = (i >> 2) & 31, d = i & 3;
        float acc = cb[d] + cw[d * 4 + 3] * xz2[b][l][d];
        if (l >= 1) acc += cw[d * 4 + 2] * xz2[b][l - 1][d];
        if (l >= 2) acc += cw[d * 4 + 1] * xz2[b][l - 2][d];
        if (l >= 3) acc += cw[d * 4 + 0] * xz2[b][l - 3][d];
        x2c[b][l][d] = silu_(acc);
    }
    __syncthreads();
    for (int i = tid; i < 4 * 32 * 33; i += 256) {
        int b = i / (32 * 33); int rem = i % (32 * 33); int l = rem / 33; int j = rem % 33;
        float s = 0.f;
        #pragma unroll
        for (int d = 0; d < 4; ++d) s += x2c[b][l][d] * xw[j * 4 + d];
        dbl2[b][l][j] = s;
    }
    __syncthreads();
    for (int i = tid; i < 4 * 32 * 4; i += 256) {
        int b = i >> 7, l = (i >> 2) & 31, d = i & 3;
        dt2[b][l][d] = softplus_(dbl2[b][l][0] * dtw[d] + dtb[d]);
    }
    __syncthreads();
    {
        int b = tid >> 6, d = (tid >> 4) & 3, n = tid & 15;
        float a2v = A2[d * 16 + n];
        float h = 0.f;
        for (int t = 0; t < 32; ++t) {
            float dtv = dt2[b][t][d];
            float a = exp2f(dtv * a2v);
            h = a * h + dtv * x2c[b][t][d] * dbl2[b][t][1 + n];
            float contrib = h * dbl2[b][t][17 + n];
            contrib += __shfl_xor(contrib, 1, 64);
            contrib += __shfl_xor(contrib, 2, 64);
            contrib += __shfl_xor(contrib, 4, 64);
            contrib += __shfl_xor(contrib, 8, 64);
            if (n == 0) y2[b][t][d] = contrib;
        }
    }
    __syncthreads();
    if (tid < 128) {
        int b = tid >> 5, l = tid & 31;
        float s = 0.f;
        #pragma unroll
        for (int d = 0; d < 4; ++d) {
            float yg = (y2[b][l][d] + x2c[b][l][d] * Dp[d]) * silu_(xz2[b][l][4 + d]);
            s += yg * (ow[d] + ow[4 + d]);
        }
        focf[b * 32 + l] = s;
    }
}

// ---------------------------------------------------------------- final: out = res*(1+foc)
__global__ __launch_bounds__(256) void k_final(const float* __restrict__ res, const float* __restrict__ focf,
                                               float* __restrict__ out) {
    int i = blockIdx.x * 256 + threadIdx.x;
    int bc = i >> 12;
    out[i] = res[i] * (1.0f + focf[bc]);
}

extern "C" void kernel_launch(void* const* d_in, const int* in_sizes, int n_in,
                              void* d_out, int out_size, void* d_ws, size_t ws_size,
                              hipStream_t stream) {
    const float* fo1      = (const float*)d_in[0];
    const float* fo2      = (const float*)d_in[1];
    const float* m1_in_w  = (const float*)d_in[2];
    const float* m1_cw    = (const float*)d_in[3];
    const float* m1_cb    = (const float*)d_in[4];
    const float* m1_xw    = (const float*)d_in[5];
    const float* m1_dtw   = (const float*)d_in[6];
    const float* m1_dtb   = (const float*)d_in[7];
    const float* m1_alog  = (const float*)d_in[8];
    const float* m1_D     = (const float*)d_in[9];
    const float* m1_ow    = (const float*)d_in[10];
    const float* m2_in_w  = (const float*)d_in[11];
    const float* m2_cw    = (const float*)d_in[12];
    const float* m2_cb    = (const float*)d_in[13];
    const float* m2_xw    = (const float*)d_in[14];
    const float* m2_dtw   = (const float*)d_in[15];
    const float* m2_dtb   = (const float*)d_in[16];
    const float* m2_alog  = (const float*)d_in[17];
    const float* m2_D     = (const float*)d_in[18];
    const float* m2_ow    = (const float*)d_in[19];

    float* ws = (float*)d_ws;
    // workspace layout (float offsets), ~101 MB total
    unsigned short* u_bf = (unsigned short*)ws;                    // 2,097,152 bf16 = 1,048,576 f
    float* xz    = ws + 1048576;       // 8,388,608
    float* xbuf  = ws + 9437184;       // 4,194,304
    unsigned short* xbf = (unsigned short*)(ws + 13631488);        // 4,194,304 bf16 = 2,097,152 f
    float* dbl   = ws + 15728640;      // 655,360
    float* dtbuf = ws + 16384000;      // 4,194,304
    float* Pb    = ws + 20578304;      // 2,097,152 ; ybf aliases (dead after scan2)
    float* Sb    = ws + 22675456;      // 2,097,152 ; carry aliases (read-before-write)
    unsigned short* ybf = (unsigned short*)Pb;
    float* carry = Sb;
    float* opre  = xz;                 // xz dead after scan3
    float* res   = ws + 24772608;      // 524,288
    float* foc0  = ws + 25296896;      // 128
    float* focf  = ws + 25297024;      // 128
    float* A2m1  = ws + 25297152;      // 4,096
    float* A2m2  = ws + 25301248;      // 64
    unsigned short* win_bf = (unsigned short*)(ws + 25301312);     // 65,536 bf16
    unsigned short* wx_bf  = (unsigned short*)(ws + 25334080);     // 10,240 bf16
    unsigned short* wo_bf  = (unsigned short*)(ws + 25339200);     // 32,768 bf16

    k_prep<<<441, 256, 0, stream>>>(m1_alog, m2_alog, m1_in_w, m1_xw, m1_ow,
                                    A2m1, A2m2, win_bf, wx_bf, wo_bf);
    k_gather<<<256, 256, 0, stream>>>(fo1, u_bf);
    {   dim3 g(4, 128);  k_gemm_mfma<<<g, 256, 0, stream>>>(u_bf, win_bf, xz, 16384, 512, 128); }
    k_conv<<<16384, 256, 0, stream>>>(xz, m1_cw, m1_cb, xbuf, xbf);
    {   dim3 g(1, 128);  k_gemm_mfma<<<g, 256, 0, stream>>>(xbf, wx_bf, dbl, 16384, 40, 256); }
    k_dtproj<<<16384, 256, 0, stream>>>(dbl, m1_dtw, m1_dtb, dtbuf);
    k_scan1<<<4 * NCH, 256, 0, stream>>>(dtbuf, xbuf, dbl, A2m1, Pb, Sb);
    k_scan2<<<64, 256, 0, stream>>>(Pb, Sb, carry);
    k_scan3<<<4 * NCH, 256, 0, stream>>>(dtbuf, xbuf, xz, dbl, A2m1, carry, m1_D, ybf);
    {   dim3 g(1, 128);  k_gemm_mfma<<<g, 256, 0, stream>>>(ybf, wo_bf, opre, 16384, 128, 256); }
    k_gsum<<<256, 256, 0, stream>>>(opre, fo2, res);
    k_rowmean<<<128, 256, 0, stream>>>(res, foc0);
    k_mamba2<<<1, 256, 0, stream>>>(foc0, m2_in_w, m2_cw, m2_cb, m2_xw, m2_dtw, m2_dtb,
                                    A2m2, m2_D, m2_ow, focf);
    k_final<<<2048, 256, 0, stream>>>(res, focf, (float*)d_out);
}

// Round 3
// 261.669 us; speedup vs baseline: 1.3884x; 1.0259x over previous
//
#include <hip/hip_runtime.h>
#include <cstdint>
#include <cstddef>

// (B,C,H,W)=(4,32,64,64); mamba1: d_model=128, d_in=256, dt_rank=8, N=16;
// mamba2: d_model=2, d_in=4, dt_rank=1.
constexpr int NCH = 128;   // L / Tchunk
constexpr int TCH = 32;    // scan chunk length

typedef __attribute__((ext_vector_type(8))) short bf16x8;
typedef __attribute__((ext_vector_type(4))) float f32x4;

static __device__ __forceinline__ float sigm_(float x) { return 1.0f / (1.0f + __expf(-x)); }
static __device__ __forceinline__ float silu_(float x) { return x * sigm_(x); }
static __device__ __forceinline__ float softplus_(float x) { return (x > 20.0f) ? x : log1pf(__expf(x)); }
static __device__ __forceinline__ unsigned short f2bf(float f) {
    union { float f; unsigned int u; } v; v.f = f;
    unsigned int r = v.u + 0x7FFFu + ((v.u >> 16) & 1u);
    return (unsigned short)(r >> 16);
}

// ---------------------------------------------------------------- prep: A2 scale, weight bf16 casts, zero foc0
__global__ void k_prep(const float* __restrict__ alog1, const float* __restrict__ alog2,
                       const float* __restrict__ w_in, const float* __restrict__ w_x,
                       const float* __restrict__ w_o,
                       float* __restrict__ A2m1, float* __restrict__ A2m2,
                       unsigned short* __restrict__ win_bf, unsigned short* __restrict__ wx_bf,
                       unsigned short* __restrict__ wo_bf, float* __restrict__ foc0) {
    int i = blockIdx.x * 256 + threadIdx.x;
    const float LOG2E = 1.4426950408889634f;
    if (i < 4096)        A2m1[i] = -__expf(alog1[i]) * LOG2E;
    else if (i < 4160)   A2m2[i - 4096] = -__expf(alog2[i - 4096]) * LOG2E;
    else if (i < 69696)  win_bf[i - 4160]  = f2bf(w_in[i - 4160]);    // 512*128
    else if (i < 79936)  wx_bf[i - 69696]  = f2bf(w_x[i - 69696]);    // 40*256
    else if (i < 112704) wo_bf[i - 79936]  = f2bf(w_o[i - 79936]);    // 128*256
    else if (i < 112832) foc0[i - 112704]  = 0.0f;
}

// ---------------------------------------------------------------- gather fo1 -> u bf16 (B, 4096, 128)
__global__ __launch_bounds__(256) void k_gather(const float* __restrict__ fo1, unsigned short* __restrict__ u) {
    __shared__ float lds[32][65];
    int blk = blockIdx.x;          // 4*64 blocks: (b, h)
    int b = blk >> 6, h = blk & 63;
    int tid = threadIdx.x;
    {
        int w = tid & 63, cs = tid >> 6;
        const float* src = fo1 + (size_t)(b * 32) * 4096 + h * 64 + w;
        #pragma unroll
        for (int j = 0; j < 8; ++j) {
            int c = cs * 8 + j;
            lds[c][w] = src[(size_t)c * 4096];
        }
    }
    __syncthreads();
    {
        int c = tid & 31, wsub = tid >> 5;
        #pragma unroll
        for (int j = 0; j < 8; ++j) {
            int w = wsub * 8 + j;
            unsigned short v = f2bf(lds[c][w]);
            int l  = h * 64 + w;
            int l2 = w * 64 + h;
            u[(size_t)(b * 4096 + l)        * 128 +       c] = v;
            u[(size_t)(b * 4096 + 4095 - l) * 128 + 32  + c] = v;
            u[(size_t)(b * 4096 + l2)       * 128 + 64  + c] = v;
            u[(size_t)(b * 4096 + 4095 - l2)* 128 + 96  + c] = v;
        }
    }
}

// ---------------------------------------------------------------- MFMA bf16 GEMM  C = A @ W^T (fp32 out)
__global__ __launch_bounds__(256) void k_gemm_mfma(const unsigned short* __restrict__ A,
                                                   const unsigned short* __restrict__ W,
                                                   float* __restrict__ Cmat, int M, int N, int K) {
    __shared__ unsigned short As[128][40];
    __shared__ unsigned short Ws[128][40];
    int n0 = blockIdx.x * 128, m0 = blockIdx.y * 128;
    int tid = threadIdx.x;
    int lane = tid & 63, wv = tid >> 6;
    int mh = wv >> 1, nh = wv & 1;
    int lm = lane & 15, quad = lane >> 4;

    f32x4 acc[4][4];
    #pragma unroll
    for (int i = 0; i < 4; ++i)
        #pragma unroll
        for (int j = 0; j < 4; ++j) acc[i][j] = (f32x4)(0.0f);

    for (int k0 = 0; k0 < K; k0 += 32) {
        #pragma unroll
        for (int j = 0; j < 2; ++j) {
            int c = tid + 256 * j;
            int row = c >> 2;
            int kc = (c & 3) * 8;
            uint4 av = *(const uint4*)&A[(size_t)(m0 + row) * K + k0 + kc];
            *(uint4*)&As[row][kc] = av;
            uint4 wvv = make_uint4(0u, 0u, 0u, 0u);
            if (n0 + row < N) wvv = *(const uint4*)&W[(size_t)(n0 + row) * K + k0 + kc];
            *(uint4*)&Ws[row][kc] = wvv;
        }
        __syncthreads();
        bf16x8 a_frag[4], b_frag[4];
        #pragma unroll
        for (int i = 0; i < 4; ++i)
            a_frag[i] = *(const bf16x8*)&As[mh * 64 + 16 * i + lm][quad * 8];
        #pragma unroll
        for (int j = 0; j < 4; ++j)
            b_frag[j] = *(const bf16x8*)&Ws[nh * 64 + 16 * j + lm][quad * 8];
        #pragma unroll
        for (int i = 0; i < 4; ++i)
            #pragma unroll
            for (int j = 0; j < 4; ++j)
                acc[i][j] = __builtin_amdgcn_mfma_f32_16x16x32_bf16(a_frag[i], b_frag[j], acc[i][j], 0, 0, 0);
        __syncthreads();
    }
    #pragma unroll
    for (int i = 0; i < 4; ++i) {
        #pragma unroll
        for (int r = 0; r < 4; ++r) {
            size_t mrow = (size_t)(m0 + mh * 64 + 16 * i + quad * 4 + r) * N;
            #pragma unroll
            for (int j = 0; j < 4; ++j) {
                int col = n0 + nh * 64 + 16 * j + lm;
                if (col < N) Cmat[mrow + col] = acc[i][j][r];
            }
        }
    }
}

// ---------------------------------------------------------------- depthwise causal conv(4) + SiLU, reg window
__global__ __launch_bounds__(256) void k_conv(const float* __restrict__ xz, const float* __restrict__ cw,
                                              const float* __restrict__ cb, float* __restrict__ x,
                                              unsigned short* __restrict__ xbf) {
    int blk = blockIdx.x;           // 512: (b, 128 l-chunks of 32)
    int b = blk >> 7, lc = blk & 127;
    int d = threadIdx.x;
    int l0 = lc * 32;
    float w0 = cw[d * 4 + 0], w1 = cw[d * 4 + 1], w2 = cw[d * 4 + 2], w3 = cw[d * 4 + 3];
    float bb = cb[d];
    size_t rbase = ((size_t)(b * 4096 + l0)) * 512 + d;
    float xm1 = (l0 >= 1) ? xz[rbase - 512]  : 0.f;
    float xm2 = (l0 >= 2) ? xz[rbase - 1024] : 0.f;
    float xm3 = (l0 >= 3) ? xz[rbase - 1536] : 0.f;
    size_t wbase = ((size_t)(b * 4096 + l0)) * 256 + d;
    for (int il = 0; il < 32; ++il) {
        float xc = xz[rbase + (size_t)il * 512];
        float v = silu_(bb + w3 * xc + w2 * xm1 + w1 * xm2 + w0 * xm3);
        x[wbase + (size_t)il * 256] = v;
        xbf[wbase + (size_t)il * 256] = f2bf(v);
        xm3 = xm2; xm2 = xm1; xm1 = xc;
    }
}

// ---------------------------------------------------------------- scan phase 1 (dt fused): per-chunk (P, S)
__global__ __launch_bounds__(256) void k_scan1(const float* __restrict__ x, const float* __restrict__ dbl,
                                               const float* __restrict__ A2, const float* __restrict__ dtw,
                                               const float* __restrict__ dtb,
                                               float* __restrict__ P, float* __restrict__ S) {
    int blk = blockIdx.x;          // b*NCH + ch
    int b = blk / NCH, ch = blk % NCH;
    int d = threadIdx.x;
    float wdt[8];
    #pragma unroll
    for (int r = 0; r < 8; ++r) wdt[r] = dtw[d * 8 + r];
    float bdt = dtb[d];
    float a2[16], h[16], p[16];
    #pragma unroll
    for (int n = 0; n < 16; ++n) { a2[n] = A2[d * 16 + n]; h[n] = 0.f; p[n] = 1.f; }
    int t0 = ch * TCH;
    for (int t = t0; t < t0 + TCH; ++t) {
        size_t row = (size_t)(b * 4096 + t);
        const float* br = dbl + row * 40;
        float4 q0 = *(const float4*)(br), q1 = *(const float4*)(br + 4);
        float4 b0 = *(const float4*)(br + 8), b1 = *(const float4*)(br + 12),
               b2 = *(const float4*)(br + 16), b3 = *(const float4*)(br + 20);
        float dtv = softplus_(q0.x * wdt[0] + q0.y * wdt[1] + q0.z * wdt[2] + q0.w * wdt[3] +
                              q1.x * wdt[4] + q1.y * wdt[5] + q1.z * wdt[6] + q1.w * wdt[7] + bdt);
        float xv = x[row * 256 + d];
        float bm[16] = {b0.x, b0.y, b0.z, b0.w, b1.x, b1.y, b1.z, b1.w,
                        b2.x, b2.y, b2.z, b2.w, b3.x, b3.y, b3.z, b3.w};
        float dx = dtv * xv;
        #pragma unroll
        for (int n = 0; n < 16; ++n) {
            float a = exp2f(dtv * a2[n]);
            h[n] = a * h[n] + dx * bm[n];
            p[n] *= a;
        }
    }
    size_t o = ((size_t)blk * 256 + d) * 16;
    #pragma unroll
    for (int n = 0; n < 16; n += 4) {
        *(float4*)&P[o + n] = make_float4(p[n], p[n + 1], p[n + 2], p[n + 3]);
        *(float4*)&S[o + n] = make_float4(h[n], h[n + 1], h[n + 2], h[n + 3]);
    }
}

// ---------------------------------------------------------------- scan phase 2: parallel LDS chunk-carry scan
// block = (b, d); 128 chunks x 16 n in LDS, Hillis-Steele over chunks.
// carry may alias S: block reads its region into LDS before writing.
__global__ __launch_bounds__(256) void k_scan2(const float* __restrict__ P, const float* S, float* carry) {
    __shared__ float Pl[2048];
    __shared__ float Sl[2048];
    int blk = blockIdx.x;          // 1024: b = blk>>8, d = blk&255
    int b = blk >> 8, d = blk & 255;
    int tid = threadIdx.x;
    int n = tid & 15, chb = tid >> 4;   // 16 chunk-groups
    #pragma unroll
    for (int g = 0; g < 8; ++g) {
        int ch = g * 16 + chb;
        size_t o = (((size_t)(b * NCH + ch)) * 256 + d) * 16 + n;
        Pl[ch * 16 + n] = P[o];
        Sl[ch * 16 + n] = S[o];
    }
    __syncthreads();
    for (int st = 1; st < NCH; st <<= 1) {
        float np[8], ns[8];
        #pragma unroll
        for (int g = 0; g < 8; ++g) {
            int ch = g * 16 + chb;
            int i = ch * 16 + n;
            float pc = Pl[i], sc = Sl[i];
            if (ch >= st) {
                float pp = Pl[i - st * 16], sp = Sl[i - st * 16];
                np[g] = pp * pc;
                ns[g] = sp * pc + sc;
            } else { np[g] = pc; ns[g] = sc; }
        }
        __syncthreads();
        #pragma unroll
        for (int g = 0; g < 8; ++g) {
            int i = (g * 16 + chb) * 16 + n;
            Pl[i] = np[g]; Sl[i] = ns[g];
        }
        __syncthreads();
    }
    #pragma unroll
    for (int g = 0; g < 8; ++g) {
        int ch = g * 16 + chb;
        size_t o = (((size_t)(b * NCH + ch)) * 256 + d) * 16 + n;
        carry[o] = (ch == 0) ? 0.f : Sl[(ch - 1) * 16 + n];
    }
}

// ---------------------------------------------------------------- scan phase 3 (dt fused): replay + epilogue
__global__ __launch_bounds__(256) void k_scan3(const float* __restrict__ x, const float* __restrict__ xz,
                                               const float* __restrict__ dbl, const float* __restrict__ A2,
                                               const float* __restrict__ dtw, const float* __restrict__ dtb,
                                               const float* __restrict__ carry, const float* __restrict__ Dp,
                                               unsigned short* __restrict__ y) {
    int blk = blockIdx.x;
    int b = blk / NCH, ch = blk % NCH;
    int d = threadIdx.x;
    float wdt[8];
    #pragma unroll
    for (int r = 0; r < 8; ++r) wdt[r] = dtw[d * 8 + r];
    float bdt = dtb[d];
    float a2[16], h[16];
    size_t co = ((size_t)blk * 256 + d) * 16;
    #pragma unroll
    for (int n = 0; n < 16; n += 4) {
        float4 v = *(const float4*)&carry[co + n];
        h[n] = v.x; h[n + 1] = v.y; h[n + 2] = v.z; h[n + 3] = v.w;
    }
    #pragma unroll
    for (int n = 0; n < 16; ++n) a2[n] = A2[d * 16 + n];
    float Dd = Dp[d];
    int t0 = ch * TCH;
    for (int t = t0; t < t0 + TCH; ++t) {
        size_t row = (size_t)(b * 4096 + t);
        const float* br = dbl + row * 40;
        float4 q0 = *(const float4*)(br), q1 = *(const float4*)(br + 4);
        float4 b0 = *(const float4*)(br + 8),  b1 = *(const float4*)(br + 12),
               b2 = *(const float4*)(br + 16), b3 = *(const float4*)(br + 20);
        float4 c0 = *(const float4*)(br + 24), c1 = *(const float4*)(br + 28),
               c2 = *(const float4*)(br + 32), c3 = *(const float4*)(br + 36);
        float dtv = softplus_(q0.x * wdt[0] + q0.y * wdt[1] + q0.z * wdt[2] + q0.w * wdt[3] +
                              q1.x * wdt[4] + q1.y * wdt[5] + q1.z * wdt[6] + q1.w * wdt[7] + bdt);
        float xv = x[row * 256 + d];
        float zv = xz[row * 512 + 256 + d];
        float bm[16] = {b0.x, b0.y, b0.z, b0.w, b1.x, b1.y, b1.z, b1.w,
                        b2.x, b2.y, b2.z, b2.w, b3.x, b3.y, b3.z, b3.w};
        float cm[16] = {c0.x, c0.y, c0.z, c0.w, c1.x, c1.y, c1.z, c1.w,
                        c2.x, c2.y, c2.z, c2.w, c3.x, c3.y, c3.z, c3.w};
        float dx = dtv * xv;
        float yv = 0.f;
        #pragma unroll
        for (int n = 0; n < 16; ++n) {
            float a = exp2f(dtv * a2[n]);
            h[n] = a * h[n] + dx * bm[n];
            yv += h[n] * cm[n];
        }
        yv = (yv + xv * Dd) * silu_(zv);
        y[row * 256 + d] = f2bf(yv);
    }
}

// ---------------------------------------------------------------- out-proj MFMA + gsum(4) + *fo2 + rowmean atomics
// A: ybf (16384,256) bf16; W: wo_bf (128,256) bf16. Writes res (B,C,H,W) and foc0 sums.
__global__ __launch_bounds__(256) void k_oproj(const unsigned short* __restrict__ A,
                                               const unsigned short* __restrict__ W,
                                               const float* __restrict__ fo2,
                                               float* __restrict__ res, float* __restrict__ foc0) {
    __shared__ unsigned short As[128][40];
    __shared__ unsigned short Ws[128][40];
    __shared__ float gs[2][128][37];
    int m0 = blockIdx.x * 128;
    int b = m0 >> 12, l0 = m0 & 4095;
    int tid = threadIdx.x;
    int lane = tid & 63, wv = tid >> 6;
    int mh = wv >> 1, nh = wv & 1;
    int lm = lane & 15, quad = lane >> 4;

    f32x4 acc[4][4];
    #pragma unroll
    for (int i = 0; i < 4; ++i)
        #pragma unroll
        for (int j = 0; j < 4; ++j) acc[i][j] = (f32x4)(0.0f);

    for (int k0 = 0; k0 < 256; k0 += 32) {
        #pragma unroll
        for (int j = 0; j < 2; ++j) {
            int c = tid + 256 * j;
            int row = c >> 2;
            int kc = (c & 3) * 8;
            *(uint4*)&As[row][kc] = *(const uint4*)&A[(size_t)(m0 + row) * 256 + k0 + kc];
            *(uint4*)&Ws[row][kc] = *(const uint4*)&W[(size_t)row * 256 + k0 + kc];
        }
        __syncthreads();
        bf16x8 a_frag[4], b_frag[4];
        #pragma unroll
        for (int i = 0; i < 4; ++i)
            a_frag[i] = *(const bf16x8*)&As[mh * 64 + 16 * i + lm][quad * 8];
        #pragma unroll
        for (int j = 0; j < 4; ++j)
            b_frag[j] = *(const bf16x8*)&Ws[nh * 64 + 16 * j + lm][quad * 8];
        #pragma unroll
        for (int i = 0; i < 4; ++i)
            #pragma unroll
            for (int j = 0; j < 4; ++j)
                acc[i][j] = __builtin_amdgcn_mfma_f32_16x16x32_bf16(a_frag[i], b_frag[j], acc[i][j], 0, 0, 0);
        __syncthreads();
    }
    // channel partials: col = 64*nh + 16*j + lm; channel c = (16j+lm)&31 -> j-pairs (0,2) and (1,3)
    #pragma unroll
    for (int i = 0; i < 4; ++i) {
        #pragma unroll
        for (int r = 0; r < 4; ++r) {
            int lr = mh * 64 + 16 * i + quad * 4 + r;
            gs[nh][lr][lm]      = acc[i][0][r] + acc[i][2][r];
            gs[nh][lr][lm + 16] = acc[i][1][r] + acc[i][3][r];
        }
    }
    __syncthreads();
    {
        int c = tid >> 3, i8 = tid & 7;   // 32 channels x 8 row-groups
        float psum = 0.f;
        size_t obase = ((size_t)(b * 32 + c)) * 4096 + l0;
        #pragma unroll
        for (int ii = 0; ii < 16; ++ii) {
            int lr = i8 * 16 + ii;
            float v = (gs[0][lr][c] + gs[1][lr][c]) * fo2[obase + lr];
            res[obase + lr] = v;
            psum += v;
        }
        psum += __shfl_xor(psum, 1, 64);
        psum += __shfl_xor(psum, 2, 64);
        psum += __shfl_xor(psum, 4, 64);
        if (i8 == 0) atomicAdd(&foc0[b * 32 + c], psum);
    }
}

// ---------------------------------------------------------------- tiny mamba2, single block (foc0 holds SUMS)
__global__ __launch_bounds__(256) void k_mamba2(const float* __restrict__ foc0,
                                                const float* __restrict__ in_w, const float* __restrict__ cw,
                                                const float* __restrict__ cb, const float* __restrict__ xw,
                                                const float* __restrict__ dtw, const float* __restrict__ dtb,
                                                const float* __restrict__ A2, const float* __restrict__ Dp,
                                                const float* __restrict__ ow, float* __restrict__ focf) {
    __shared__ float xz2[4][32][8];
    __shared__ float x2c[4][32][4];
    __shared__ float dbl2[4][32][33];
    __shared__ float dt2[4][32][4];
    __shared__ float y2[4][32][4];
    int tid = threadIdx.x;
    const float SC = 1.0f / 4096.0f;
    for (int i = tid; i < 4 * 32 * 8; i += 256) {
        int b = i >> 8, l = (i >> 3) & 31, j = i & 7;
        float u0 = foc0[b * 32 + l] * SC, u1 = foc0[b * 32 + 31 - l] * SC;
        xz2[b][l][j] = u0 * in_w[j * 2] + u1 * in_w[j * 2 + 1];
    }
    __syncthreads();
    for (int i = tid; i < 4 * 32 * 4; i += 256) {
        int b = i >> 7, l = (i >> 2) & 31, d = i & 3;
        float acc = cb[d] + cw[d * 4 + 3] * xz2[b][l][d];
        if (l >= 1) acc += cw[d * 4 + 2] * xz2[b][l - 1][d];
        if (l >= 2) acc += cw[d * 4 + 1] * xz2[b][l - 2][d];
        if (l >= 3) acc += cw[d * 4 + 0] * xz2[b][l - 3][d];
        x2c[b][l][d] = silu_(acc);
    }
    __syncthreads();
    for (int i = tid; i < 4 * 32 * 33; i += 256) {
        int b = i / (32 * 33); int rem = i % (32 * 33); int l = rem / 33; int j = rem % 33;
        float s = 0.f;
        #pragma unroll
        for (int d = 0; d < 4; ++d) s += x2c[b][l][d] * xw[j * 4 + d];
        dbl2[b][l][j] = s;
    }
    __syncthreads();
    for (int i = tid; i < 4 * 32 * 4; i += 256) {
        int b = i >> 7, l = (i >> 2) & 31, d = i & 3;
        dt2[b][l][d] = softplus_(dbl2[b][l][0] * dtw[d] + dtb[d]);
    }
    __syncthreads();
    {
        int b = tid >> 6, d = (tid >> 4) & 3, n = tid & 15;
        float a2v = A2[d * 16 + n];
        float h = 0.f;
        for (int t = 0; t < 32; ++t) {
            float dtv = dt2[b][t][d];
            float a = exp2f(dtv * a2v);
            h = a * h + dtv * x2c[b][t][d] * dbl2[b][t][1 + n];
            float contrib = h * dbl2[b][t][17 + n];
            contrib += __shfl_xor(contrib, 1, 64);
            contrib += __shfl_xor(contrib, 2, 64);
            contrib += __shfl_xor(contrib, 4, 64);
            contrib += __shfl_xor(contrib, 8, 64);
            if (n == 0) y2[b][t][d] = contrib;
        }
    }
    __syncthreads();
    if (tid < 128) {
        int b = tid >> 5, l = tid & 31;
        float s = 0.f;
        #pragma unroll
        for (int d = 0; d < 4; ++d) {
            float yg = (y2[b][l][d] + x2c[b][l][d] * Dp[d]) * silu_(xz2[b][l][4 + d]);
            s += yg * (ow[d] + ow[4 + d]);
        }
        focf[b * 32 + l] = s;
    }
}

// ---------------------------------------------------------------- final: out = res*(1+foc)
__global__ __launch_bounds__(256) void k_final(const float* __restrict__ res, const float* __restrict__ focf,
                                               float* __restrict__ out) {
    int i = blockIdx.x * 256 + threadIdx.x;
    int bc = i >> 12;
    out[i] = res[i] * (1.0f + focf[bc]);
}

extern "C" void kernel_launch(void* const* d_in, const int* in_sizes, int n_in,
                              void* d_out, int out_size, void* d_ws, size_t ws_size,
                              hipStream_t stream) {
    const float* fo1      = (const float*)d_in[0];
    const float* fo2      = (const float*)d_in[1];
    const float* m1_in_w  = (const float*)d_in[2];
    const float* m1_cw    = (const float*)d_in[3];
    const float* m1_cb    = (const float*)d_in[4];
    const float* m1_xw    = (const float*)d_in[5];
    const float* m1_dtw   = (const float*)d_in[6];
    const float* m1_dtb   = (const float*)d_in[7];
    const float* m1_alog  = (const float*)d_in[8];
    const float* m1_D     = (const float*)d_in[9];
    const float* m1_ow    = (const float*)d_in[10];
    const float* m2_in_w  = (const float*)d_in[11];
    const float* m2_cw    = (const float*)d_in[12];
    const float* m2_cb    = (const float*)d_in[13];
    const float* m2_xw    = (const float*)d_in[14];
    const float* m2_dtw   = (const float*)d_in[15];
    const float* m2_dtb   = (const float*)d_in[16];
    const float* m2_alog  = (const float*)d_in[17];
    const float* m2_D     = (const float*)d_in[18];
    const float* m2_ow    = (const float*)d_in[19];

    float* ws = (float*)d_ws;
    // workspace layout (float offsets), ~85 MB total
    unsigned short* u_bf = (unsigned short*)ws;                    // [0, 1048576)
    float* xz    = ws + 1048576;       // 8,388,608
    float* xbuf  = ws + 9437184;       // 4,194,304
    unsigned short* xbf = (unsigned short*)(ws + 13631488);        // 4,194,304 bf16
    float* dbl   = ws + 15728640;      // 655,360
    float* Pb    = ws + 16384000;      // 2,097,152 ; ybf aliases (dead after scan2)
    float* Sb    = ws + 18481152;      // 2,097,152 ; carry aliases (read-before-write in scan2)
    unsigned short* ybf = (unsigned short*)Pb;
    float* carry = Sb;
    float* res   = ws + 20578304;      // 524,288
    float* foc0  = ws + 21102592;      // 128 (zeroed by k_prep)
    float* focf  = ws + 21102720;      // 128
    float* A2m1  = ws + 21102848;      // 4,096
    float* A2m2  = ws + 21106944;      // 64
    unsigned short* win_bf = (unsigned short*)(ws + 21107008);     // 65,536 bf16
    unsigned short* wx_bf  = (unsigned short*)(ws + 21139776);     // 10,240 bf16
    unsigned short* wo_bf  = (unsigned short*)(ws + 21144896);     // 32,768 bf16

    k_prep<<<441, 256, 0, stream>>>(m1_alog, m2_alog, m1_in_w, m1_xw, m1_ow,
                                    A2m1, A2m2, win_bf, wx_bf, wo_bf, foc0);
    k_gather<<<256, 256, 0, stream>>>(fo1, u_bf);
    {   dim3 g(4, 128);  k_gemm_mfma<<<g, 256, 0, stream>>>(u_bf, win_bf, xz, 16384, 512, 128); }
    k_conv<<<512, 256, 0, stream>>>(xz, m1_cw, m1_cb, xbuf, xbf);
    {   dim3 g(1, 128);  k_gemm_mfma<<<g, 256, 0, stream>>>(xbf, wx_bf, dbl, 16384, 40, 256); }
    k_scan1<<<4 * NCH, 256, 0, stream>>>(xbuf, dbl, A2m1, m1_dtw, m1_dtb, Pb, Sb);
    k_scan2<<<1024, 256, 0, stream>>>(Pb, Sb, carry);
    k_scan3<<<4 * NCH, 256, 0, stream>>>(xbuf, xz, dbl, A2m1, m1_dtw, m1_dtb, carry, m1_D, ybf);
    k_oproj<<<128, 256, 0, stream>>>(ybf, wo_bf, fo2, res, foc0);
    k_mamba2<<<1, 256, 0, stream>>>(foc0, m2_in_w, m2_cw, m2_cb, m2_xw, m2_dtw, m2_dtb,
                                    A2m2, m2_D, m2_ow, focf);
    k_final<<<2048, 256, 0, stream>>>(res, focf, (float*)d_out);
}

// Round 4
// 249.168 us; speedup vs baseline: 1.4580x; 1.0502x over previous
//
#include <hip/hip_runtime.h>
#include <cstdint>
#include <cstddef>

// (B,C,H,W)=(4,32,64,64); mamba1: d_model=128, d_in=256, dt_rank=8, N=16;
// mamba2: d_model=2, d_in=4, dt_rank=1.
constexpr int NCH = 256;   // number of scan chunks per (b)
constexpr int TCH = 16;    // scan chunk length

typedef __attribute__((ext_vector_type(8))) short bf16x8;
typedef __attribute__((ext_vector_type(4))) float f32x4;

static __device__ __forceinline__ float sigm_(float x) { return 1.0f / (1.0f + __expf(-x)); }
static __device__ __forceinline__ float silu_(float x) { return x * sigm_(x); }
static __device__ __forceinline__ float softplus_(float x) { return (x > 20.0f) ? x : log1pf(__expf(x)); }
static __device__ __forceinline__ unsigned short f2bf(float f) {
    union { float f; unsigned int u; } v; v.f = f;
    unsigned int r = v.u + 0x7FFFu + ((v.u >> 16) & 1u);
    return (unsigned short)(r >> 16);
}
static __device__ __forceinline__ float bf2f(unsigned short s) {
    union { unsigned int u; float f; } v; v.u = ((unsigned int)s) << 16;
    return v.f;
}

// ---------------------------------------------------------------- prep: A2 scale, weight bf16 casts, zero foc0
__global__ void k_prep(const float* __restrict__ alog1, const float* __restrict__ alog2,
                       const float* __restrict__ w_in, const float* __restrict__ w_x,
                       const float* __restrict__ w_o,
                       float* __restrict__ A2m1, float* __restrict__ A2m2,
                       unsigned short* __restrict__ win_bf, unsigned short* __restrict__ wx_bf,
                       unsigned short* __restrict__ wo_bf, float* __restrict__ foc0) {
    int i = blockIdx.x * 256 + threadIdx.x;
    const float LOG2E = 1.4426950408889634f;
    if (i < 4096)        A2m1[i] = -__expf(alog1[i]) * LOG2E;
    else if (i < 4160)   A2m2[i - 4096] = -__expf(alog2[i - 4096]) * LOG2E;
    else if (i < 69696)  win_bf[i - 4160]  = f2bf(w_in[i - 4160]);    // 512*128
    else if (i < 79936)  wx_bf[i - 69696]  = f2bf(w_x[i - 69696]);    // 40*256
    else if (i < 112704) wo_bf[i - 79936]  = f2bf(w_o[i - 79936]);    // 128*256
    else if (i < 112832) foc0[i - 112704]  = 0.0f;
}

// ---------------------------------------------------------------- gather fo1 -> u bf16 (B, 4096, 128)
__global__ __launch_bounds__(256) void k_gather(const float* __restrict__ fo1, unsigned short* __restrict__ u) {
    __shared__ float lds[32][65];
    int blk = blockIdx.x;          // 4*64 blocks: (b, h)
    int b = blk >> 6, h = blk & 63;
    int tid = threadIdx.x;
    {
        int w = tid & 63, cs = tid >> 6;
        const float* src = fo1 + (size_t)(b * 32) * 4096 + h * 64 + w;
        #pragma unroll
        for (int j = 0; j < 8; ++j) {
            int c = cs * 8 + j;
            lds[c][w] = src[(size_t)c * 4096];
        }
    }
    __syncthreads();
    {
        int c = tid & 31, wsub = tid >> 5;
        #pragma unroll
        for (int j = 0; j < 8; ++j) {
            int w = wsub * 8 + j;
            unsigned short v = f2bf(lds[c][w]);
            int l  = h * 64 + w;
            int l2 = w * 64 + h;
            u[(size_t)(b * 4096 + l)        * 128 +       c] = v;
            u[(size_t)(b * 4096 + 4095 - l) * 128 + 32  + c] = v;
            u[(size_t)(b * 4096 + l2)       * 128 + 64  + c] = v;
            u[(size_t)(b * 4096 + 4095 - l2)* 128 + 96  + c] = v;
        }
    }
}

// ---------------------------------------------------------------- MFMA bf16 GEMM  C = A @ W^T (fp32 out)
__global__ __launch_bounds__(256) void k_gemm_mfma(const unsigned short* __restrict__ A,
                                                   const unsigned short* __restrict__ W,
                                                   float* __restrict__ Cmat, int M, int N, int K) {
    __shared__ unsigned short As[128][40];
    __shared__ unsigned short Ws[128][40];
    int n0 = blockIdx.x * 128, m0 = blockIdx.y * 128;
    int tid = threadIdx.x;
    int lane = tid & 63, wv = tid >> 6;
    int mh = wv >> 1, nh = wv & 1;
    int lm = lane & 15, quad = lane >> 4;

    f32x4 acc[4][4];
    #pragma unroll
    for (int i = 0; i < 4; ++i)
        #pragma unroll
        for (int j = 0; j < 4; ++j) acc[i][j] = (f32x4)(0.0f);

    for (int k0 = 0; k0 < K; k0 += 32) {
        #pragma unroll
        for (int j = 0; j < 2; ++j) {
            int c = tid + 256 * j;
            int row = c >> 2;
            int kc = (c & 3) * 8;
            uint4 av = *(const uint4*)&A[(size_t)(m0 + row) * K + k0 + kc];
            *(uint4*)&As[row][kc] = av;
            uint4 wvv = make_uint4(0u, 0u, 0u, 0u);
            if (n0 + row < N) wvv = *(const uint4*)&W[(size_t)(n0 + row) * K + k0 + kc];
            *(uint4*)&Ws[row][kc] = wvv;
        }
        __syncthreads();
        bf16x8 a_frag[4], b_frag[4];
        #pragma unroll
        for (int i = 0; i < 4; ++i)
            a_frag[i] = *(const bf16x8*)&As[mh * 64 + 16 * i + lm][quad * 8];
        #pragma unroll
        for (int j = 0; j < 4; ++j)
            b_frag[j] = *(const bf16x8*)&Ws[nh * 64 + 16 * j + lm][quad * 8];
        #pragma unroll
        for (int i = 0; i < 4; ++i)
            #pragma unroll
            for (int j = 0; j < 4; ++j)
                acc[i][j] = __builtin_amdgcn_mfma_f32_16x16x32_bf16(a_frag[i], b_frag[j], acc[i][j], 0, 0, 0);
        __syncthreads();
    }
    #pragma unroll
    for (int i = 0; i < 4; ++i) {
        #pragma unroll
        for (int r = 0; r < 4; ++r) {
            size_t mrow = (size_t)(m0 + mh * 64 + 16 * i + quad * 4 + r) * N;
            #pragma unroll
            for (int j = 0; j < 4; ++j) {
                int col = n0 + nh * 64 + 16 * j + lm;
                if (col < N) Cmat[mrow + col] = acc[i][j][r];
            }
        }
    }
}

// ---------------------------------------------------------------- depthwise causal conv(4) + SiLU -> bf16 x
__global__ __launch_bounds__(256) void k_conv(const float* __restrict__ xz, const float* __restrict__ cw,
                                              const float* __restrict__ cb,
                                              unsigned short* __restrict__ xbf) {
    int blk = blockIdx.x;           // 512: (b, 128 l-chunks of 32)
    int b = blk >> 7, lc = blk & 127;
    int d = threadIdx.x;
    int l0 = lc * 32;
    float w0 = cw[d * 4 + 0], w1 = cw[d * 4 + 1], w2 = cw[d * 4 + 2], w3 = cw[d * 4 + 3];
    float bb = cb[d];
    size_t rbase = ((size_t)(b * 4096 + l0)) * 512 + d;
    float xm1 = (l0 >= 1) ? xz[rbase - 512]  : 0.f;
    float xm2 = (l0 >= 2) ? xz[rbase - 1024] : 0.f;
    float xm3 = (l0 >= 3) ? xz[rbase - 1536] : 0.f;
    size_t wbase = ((size_t)(b * 4096 + l0)) * 256 + d;
    for (int il = 0; il < 32; ++il) {
        float xc = xz[rbase + (size_t)il * 512];
        float v = silu_(bb + w3 * xc + w2 * xm1 + w1 * xm2 + w0 * xm3);
        xbf[wbase + (size_t)il * 256] = f2bf(v);
        xm3 = xm2; xm2 = xm1; xm1 = xc;
    }
}

// ---------------------------------------------------------------- dt = softplus(dbl[:, :8] @ dt_w^T + dt_b)
__global__ __launch_bounds__(256) void k_dtproj(const float* __restrict__ dbl, const float* __restrict__ dtw,
                                                const float* __restrict__ dtb, float* __restrict__ dt) {
    int blk = blockIdx.x;          // b*4096 + l
    int d = threadIdx.x;
    const float* r = dbl + (size_t)blk * 40;
    float4 q0 = *(const float4*)(r);
    float4 q1 = *(const float4*)(r + 4);
    float4 w0 = *(const float4*)(dtw + d * 8);
    float4 w1 = *(const float4*)(dtw + d * 8 + 4);
    float v = q0.x * w0.x + q0.y * w0.y + q0.z * w0.z + q0.w * w0.w +
              q1.x * w1.x + q1.y * w1.y + q1.z * w1.z + q1.w * w1.w + dtb[d];
    dt[(size_t)blk * 256 + d] = softplus_(v);
}

// ---------------------------------------------------------------- scan phase 1: per-chunk (P, S)
__global__ __launch_bounds__(256) void k_scan1(const float* __restrict__ dt, const unsigned short* __restrict__ xbf,
                                               const float* __restrict__ dbl, const float* __restrict__ A2,
                                               float* __restrict__ P, float* __restrict__ S) {
    int blk = blockIdx.x;          // b*NCH + ch  (1024 blocks)
    int b = blk >> 8, ch = blk & 255;
    int d = threadIdx.x;
    float a2[16], h[16];
    #pragma unroll
    for (int n = 0; n < 16; ++n) { a2[n] = A2[d * 16 + n]; h[n] = 0.f; }
    float sdt = 0.f;
    int t0 = ch * TCH;
    for (int t = t0; t < t0 + TCH; ++t) {
        size_t row = (size_t)(b * 4096 + t);
        float dtv = dt[row * 256 + d];
        float xv  = bf2f(xbf[row * 256 + d]);
        const float* br = dbl + row * 40 + 8;
        float4 b0 = *(const float4*)(br), b1 = *(const float4*)(br + 4),
               b2 = *(const float4*)(br + 8), b3 = *(const float4*)(br + 12);
        float bm[16] = {b0.x, b0.y, b0.z, b0.w, b1.x, b1.y, b1.z, b1.w,
                        b2.x, b2.y, b2.z, b2.w, b3.x, b3.y, b3.z, b3.w};
        float dx = dtv * xv;
        sdt += dtv;
        #pragma unroll
        for (int n = 0; n < 16; ++n) {
            float a = exp2f(dtv * a2[n]);
            h[n] = a * h[n] + dx * bm[n];
        }
    }
    size_t o = ((size_t)blk * 256 + d) * 16;
    #pragma unroll
    for (int n = 0; n < 16; n += 4) {
        *(float4*)&P[o + n] = make_float4(exp2f(a2[n] * sdt), exp2f(a2[n + 1] * sdt),
                                          exp2f(a2[n + 2] * sdt), exp2f(a2[n + 3] * sdt));
        *(float4*)&S[o + n] = make_float4(h[n], h[n + 1], h[n + 2], h[n + 3]);
    }
}

// ---------------------------------------------------------------- scan phase 2: parallel LDS chunk-carry scan
// block = (b, d); 256 chunks x 16 n in LDS, Hillis-Steele over chunks.
// carry may alias S: block reads its whole region into LDS before writing.
__global__ __launch_bounds__(256) void k_scan2(const float* __restrict__ P, const float* S, float* carry) {
    __shared__ float Pl[NCH * 16];
    __shared__ float Sl[NCH * 16];
    int blk = blockIdx.x;          // 1024: b = blk>>8, d = blk&255
    int b = blk >> 8, d = blk & 255;
    int tid = threadIdx.x;
    int n = tid & 15, chb = tid >> 4;   // 16 chunk-groups
    #pragma unroll
    for (int g = 0; g < 16; ++g) {
        int ch = g * 16 + chb;
        size_t o = (((size_t)(b * NCH + ch)) * 256 + d) * 16 + n;
        Pl[ch * 16 + n] = P[o];
        Sl[ch * 16 + n] = S[o];
    }
    __syncthreads();
    for (int st = 1; st < NCH; st <<= 1) {
        float np[16], ns[16];
        #pragma unroll
        for (int g = 0; g < 16; ++g) {
            int ch = g * 16 + chb;
            int i = ch * 16 + n;
            float pc = Pl[i], sc = Sl[i];
            if (ch >= st) {
                float pp = Pl[i - st * 16], sp = Sl[i - st * 16];
                np[g] = pp * pc;
                ns[g] = sp * pc + sc;
            } else { np[g] = pc; ns[g] = sc; }
        }
        __syncthreads();
        #pragma unroll
        for (int g = 0; g < 16; ++g) {
            int i = (g * 16 + chb) * 16 + n;
            Pl[i] = np[g]; Sl[i] = ns[g];
        }
        __syncthreads();
    }
    #pragma unroll
    for (int g = 0; g < 16; ++g) {
        int ch = g * 16 + chb;
        size_t o = (((size_t)(b * NCH + ch)) * 256 + d) * 16 + n;
        carry[o] = (ch == 0) ? 0.f : Sl[(ch - 1) * 16 + n];
    }
}

// ---------------------------------------------------------------- scan phase 3: replay + fused epilogue (bf16 y out)
__global__ __launch_bounds__(256) void k_scan3(const float* __restrict__ dt, const unsigned short* __restrict__ xbf,
                                               const float* __restrict__ xz, const float* __restrict__ dbl,
                                               const float* __restrict__ A2, const float* __restrict__ carry,
                                               const float* __restrict__ Dp, unsigned short* __restrict__ y) {
    int blk = blockIdx.x;          // 1024
    int b = blk >> 8, ch = blk & 255;
    int d = threadIdx.x;
    float a2[16], h[16];
    size_t co = ((size_t)blk * 256 + d) * 16;
    #pragma unroll
    for (int n = 0; n < 16; n += 4) {
        float4 v = *(const float4*)&carry[co + n];
        h[n] = v.x; h[n + 1] = v.y; h[n + 2] = v.z; h[n + 3] = v.w;
    }
    #pragma unroll
    for (int n = 0; n < 16; ++n) a2[n] = A2[d * 16 + n];
    float Dd = Dp[d];
    int t0 = ch * TCH;
    for (int t = t0; t < t0 + TCH; ++t) {
        size_t row = (size_t)(b * 4096 + t);
        float dtv = dt[row * 256 + d];
        float xv  = bf2f(xbf[row * 256 + d]);
        float zv  = xz[row * 512 + 256 + d];
        const float* br = dbl + row * 40 + 8;
        float4 b0 = *(const float4*)(br),      b1 = *(const float4*)(br + 4),
               b2 = *(const float4*)(br + 8),  b3 = *(const float4*)(br + 12);
        float4 c0 = *(const float4*)(br + 16), c1 = *(const float4*)(br + 20),
               c2 = *(const float4*)(br + 24), c3 = *(const float4*)(br + 28);
        float bm[16] = {b0.x, b0.y, b0.z, b0.w, b1.x, b1.y, b1.z, b1.w,
                        b2.x, b2.y, b2.z, b2.w, b3.x, b3.y, b3.z, b3.w};
        float cm[16] = {c0.x, c0.y, c0.z, c0.w, c1.x, c1.y, c1.z, c1.w,
                        c2.x, c2.y, c2.z, c2.w, c3.x, c3.y, c3.z, c3.w};
        float dx = dtv * xv;
        float yv = 0.f;
        #pragma unroll
        for (int n = 0; n < 16; ++n) {
            float a = exp2f(dtv * a2[n]);
            h[n] = a * h[n] + dx * bm[n];
            yv += h[n] * cm[n];
        }
        yv = (yv + xv * Dd) * silu_(zv);
        y[row * 256 + d] = f2bf(yv);
    }
}

// ---------------------------------------------------------------- out-proj MFMA + gsum(4) + *fo2 + rowmean atomics
__global__ __launch_bounds__(256) void k_oproj(const unsigned short* __restrict__ A,
                                               const unsigned short* __restrict__ W,
                                               const float* __restrict__ fo2,
                                               float* __restrict__ res, float* __restrict__ foc0) {
    __shared__ unsigned short As[128][40];
    __shared__ unsigned short Ws[128][40];
    __shared__ float gs[2][128][37];
    int m0 = blockIdx.x * 128;
    int b = m0 >> 12, l0 = m0 & 4095;
    int tid = threadIdx.x;
    int lane = tid & 63, wv = tid >> 6;
    int mh = wv >> 1, nh = wv & 1;
    int lm = lane & 15, quad = lane >> 4;

    f32x4 acc[4][4];
    #pragma unroll
    for (int i = 0; i < 4; ++i)
        #pragma unroll
        for (int j = 0; j < 4; ++j) acc[i][j] = (f32x4)(0.0f);

    for (int k0 = 0; k0 < 256; k0 += 32) {
        #pragma unroll
        for (int j = 0; j < 2; ++j) {
            int c = tid + 256 * j;
            int row = c >> 2;
            int kc = (c & 3) * 8;
            *(uint4*)&As[row][kc] = *(const uint4*)&A[(size_t)(m0 + row) * 256 + k0 + kc];
            *(uint4*)&Ws[row][kc] = *(const uint4*)&W[(size_t)row * 256 + k0 + kc];
        }
        __syncthreads();
        bf16x8 a_frag[4], b_frag[4];
        #pragma unroll
        for (int i = 0; i < 4; ++i)
            a_frag[i] = *(const bf16x8*)&As[mh * 64 + 16 * i + lm][quad * 8];
        #pragma unroll
        for (int j = 0; j < 4; ++j)
            b_frag[j] = *(const bf16x8*)&Ws[nh * 64 + 16 * j + lm][quad * 8];
        #pragma unroll
        for (int i = 0; i < 4; ++i)
            #pragma unroll
            for (int j = 0; j < 4; ++j)
                acc[i][j] = __builtin_amdgcn_mfma_f32_16x16x32_bf16(a_frag[i], b_frag[j], acc[i][j], 0, 0, 0);
        __syncthreads();
    }
    #pragma unroll
    for (int i = 0; i < 4; ++i) {
        #pragma unroll
        for (int r = 0; r < 4; ++r) {
            int lr = mh * 64 + 16 * i + quad * 4 + r;
            gs[nh][lr][lm]      = acc[i][0][r] + acc[i][2][r];
            gs[nh][lr][lm + 16] = acc[i][1][r] + acc[i][3][r];
        }
    }
    __syncthreads();
    {
        int c = tid >> 3, i8 = tid & 7;   // 32 channels x 8 row-groups
        float psum = 0.f;
        size_t obase = ((size_t)(b * 32 + c)) * 4096 + l0;
        #pragma unroll
        for (int ii = 0; ii < 16; ++ii) {
            int lr = i8 * 16 + ii;
            float v = (gs[0][lr][c] + gs[1][lr][c]) * fo2[obase + lr];
            res[obase + lr] = v;
            psum += v;
        }
        psum += __shfl_xor(psum, 1, 64);
        psum += __shfl_xor(psum, 2, 64);
        psum += __shfl_xor(psum, 4, 64);
        if (i8 == 0) atomicAdd(&foc0[b * 32 + c], psum);
    }
}

// ---------------------------------------------------------------- tiny mamba2, single block (foc0 holds SUMS)
__global__ __launch_bounds__(256) void k_mamba2(const float* __restrict__ foc0,
                                                const float* __restrict__ in_w, const float* __restrict__ cw,
                                                const float* __restrict__ cb, const float* __restrict__ xw,
                                                const float* __restrict__ dtw, const float* __restrict__ dtb,
                                                const float* __restrict__ A2, const float* __restrict__ Dp,
                                                const float* __restrict__ ow, float* __restrict__ focf) {
    __shared__ float xz2[4][32][8];
    __shared__ float x2c[4][32][4];
    __shared__ float dbl2[4][32][33];
    __shared__ float dt2[4][32][4];
    __shared__ float y2[4][32][4];
    int tid = threadIdx.x;
    const float SC = 1.0f / 4096.0f;
    for (int i = tid; i < 4 * 32 * 8; i += 256) {
        int b = i >> 8, l = (i >> 3) & 31, j = i & 7;
        float u0 = foc0[b * 32 + l] * SC, u1 = foc0[b * 32 + 31 - l] * SC;
        xz2[b][l][j] = u0 * in_w[j * 2] + u1 * in_w[j * 2 + 1];
    }
    __syncthreads();
    for (int i = tid; i < 4 * 32 * 4; i += 256) {
        int b = i >> 7, l = (i >> 2) & 31, d = i & 3;
        float acc = cb[d] + cw[d * 4 + 3] * xz2[b][l][d];
        if (l >= 1) acc += cw[d * 4 + 2] * xz2[b][l - 1][d];
        if (l >= 2) acc += cw[d * 4 + 1] * xz2[b][l - 2][d];
        if (l >= 3) acc += cw[d * 4 + 0] * xz2[b][l - 3][d];
        x2c[b][l][d] = silu_(acc);
    }
    __syncthreads();
    for (int i = tid; i < 4 * 32 * 33; i += 256) {
        int b = i / (32 * 33); int rem = i % (32 * 33); int l = rem / 33; int j = rem % 33;
        float s = 0.f;
        #pragma unroll
        for (int d = 0; d < 4; ++d) s += x2c[b][l][d] * xw[j * 4 + d];
        dbl2[b][l][j] = s;
    }
    __syncthreads();
    for (int i = tid; i < 4 * 32 * 4; i += 256) {
        int b = i >> 7, l = (i >> 2) & 31, d = i & 3;
        dt2[b][l][d] = softplus_(dbl2[b][l][0] * dtw[d] + dtb[d]);
    }
    __syncthreads();
    {
        int b = tid >> 6, d = (tid >> 4) & 3, n = tid & 15;
        float a2v = A2[d * 16 + n];
        float h = 0.f;
        for (int t = 0; t < 32; ++t) {
            float dtv = dt2[b][t][d];
            float a = exp2f(dtv * a2v);
            h = a * h + dtv * x2c[b][t][d] * dbl2[b][t][1 + n];
            float contrib = h * dbl2[b][t][17 + n];
            contrib += __shfl_xor(contrib, 1, 64);
            contrib += __shfl_xor(contrib, 2, 64);
            contrib += __shfl_xor(contrib, 4, 64);
            contrib += __shfl_xor(contrib, 8, 64);
            if (n == 0) y2[b][t][d] = contrib;
        }
    }
    __syncthreads();
    if (tid < 128) {
        int b = tid >> 5, l = tid & 31;
        float s = 0.f;
        #pragma unroll
        for (int d = 0; d < 4; ++d) {
            float yg = (y2[b][l][d] + x2c[b][l][d] * Dp[d]) * silu_(xz2[b][l][4 + d]);
            s += yg * (ow[d] + ow[4 + d]);
        }
        focf[b * 32 + l] = s;
    }
}

// ---------------------------------------------------------------- final: out = res*(1+foc)
__global__ __launch_bounds__(256) void k_final(const float* __restrict__ res, const float* __restrict__ focf,
                                               float* __restrict__ out) {
    int i = blockIdx.x * 256 + threadIdx.x;
    int bc = i >> 12;
    out[i] = res[i] * (1.0f + focf[bc]);
}

extern "C" void kernel_launch(void* const* d_in, const int* in_sizes, int n_in,
                              void* d_out, int out_size, void* d_ws, size_t ws_size,
                              hipStream_t stream) {
    const float* fo1      = (const float*)d_in[0];
    const float* fo2      = (const float*)d_in[1];
    const float* m1_in_w  = (const float*)d_in[2];
    const float* m1_cw    = (const float*)d_in[3];
    const float* m1_cb    = (const float*)d_in[4];
    const float* m1_xw    = (const float*)d_in[5];
    const float* m1_dtw   = (const float*)d_in[6];
    const float* m1_dtb   = (const float*)d_in[7];
    const float* m1_alog  = (const float*)d_in[8];
    const float* m1_D     = (const float*)d_in[9];
    const float* m1_ow    = (const float*)d_in[10];
    const float* m2_in_w  = (const float*)d_in[11];
    const float* m2_cw    = (const float*)d_in[12];
    const float* m2_cb    = (const float*)d_in[13];
    const float* m2_xw    = (const float*)d_in[14];
    const float* m2_dtw   = (const float*)d_in[15];
    const float* m2_dtb   = (const float*)d_in[16];
    const float* m2_alog  = (const float*)d_in[17];
    const float* m2_D     = (const float*)d_in[18];
    const float* m2_ow    = (const float*)d_in[19];

    float* ws = (float*)d_ws;
    // workspace layout (float offsets), ~101 MB total
    unsigned short* u_bf = (unsigned short*)ws;                    // [0, 1048576)
    float* xz    = ws + 1048576;       // 8,388,608
    unsigned short* xbf = (unsigned short*)(ws + 9437184);         // 4,194,304 bf16 = 2,097,152 f
    float* dbl   = ws + 11534336;      // 655,360
    float* dtbuf = ws + 12189696;      // 4,194,304
    float* Pb    = ws + 16384000;      // 4,194,304 ; ybf aliases (dead after scan2)
    float* Sb    = ws + 20578304;      // 4,194,304 ; carry aliases (block-local read-before-write in scan2)
    unsigned short* ybf = (unsigned short*)Pb;
    float* carry = Sb;
    float* opre  = xz;                 // unused name retained
    (void)opre;
    float* res   = ws + 24772608;      // 524,288
    float* foc0  = ws + 25296896;      // 128 (zeroed by k_prep)
    float* focf  = ws + 25297024;      // 128
    float* A2m1  = ws + 25297152;      // 4,096
    float* A2m2  = ws + 25301248;      // 64
    unsigned short* win_bf = (unsigned short*)(ws + 25301312);     // 65,536 bf16
    unsigned short* wx_bf  = (unsigned short*)(ws + 25334080);     // 10,240 bf16
    unsigned short* wo_bf  = (unsigned short*)(ws + 25339200);     // 32,768 bf16

    k_prep<<<441, 256, 0, stream>>>(m1_alog, m2_alog, m1_in_w, m1_xw, m1_ow,
                                    A2m1, A2m2, win_bf, wx_bf, wo_bf, foc0);
    k_gather<<<256, 256, 0, stream>>>(fo1, u_bf);
    {   dim3 g(4, 128);  k_gemm_mfma<<<g, 256, 0, stream>>>(u_bf, win_bf, xz, 16384, 512, 128); }
    k_conv<<<512, 256, 0, stream>>>(xz, m1_cw, m1_cb, xbf);
    {   dim3 g(1, 128);  k_gemm_mfma<<<g, 256, 0, stream>>>(xbf, wx_bf, dbl, 16384, 40, 256); }
    k_dtproj<<<16384, 256, 0, stream>>>(dbl, m1_dtw, m1_dtb, dtbuf);
    k_scan1<<<4 * NCH, 256, 0, stream>>>(dtbuf, xbf, dbl, A2m1, Pb, Sb);
    k_scan2<<<1024, 256, 0, stream>>>(Pb, Sb, carry);
    k_scan3<<<4 * NCH, 256, 0, stream>>>(dtbuf, xbf, xz, dbl, A2m1, carry, m1_D, ybf);
    k_oproj<<<128, 256, 0, stream>>>(ybf, wo_bf, fo2, res, foc0);
    k_mamba2<<<1, 256, 0, stream>>>(foc0, m2_in_w, m2_cw, m2_cb, m2_xw, m2_dtw, m2_dtb,
                                    A2m2, m2_D, m2_ow, focf);
    k_final<<<2048, 256, 0, stream>>>(res, focf, (float*)d_out);
}